// Round 1
// baseline (1529.552 us; speedup 1.0000x reference)
//
#include <hip/hip_runtime.h>
#include <hip/hip_bf16.h>
#include <cstdint>

// Problem constants
#define BATCH 8
#define SEQ   2048
#define DM    512
#define DAUX  64
#define MROWS (BATCH * SEQ)   // 16384
#define MASKVAL -3.402823466e38f

// ---------------------------------------------------------------------------
// K1: C[i,j] = sum_d X[i,d] * W[j,d] + bias[j]   (M=16384, N=512, K=512)
// 64x64 block tile, 256 threads, 4x4 micro-tile, K-chunks of 32.
// ---------------------------------------------------------------------------
__global__ __launch_bounds__(256) void qkv_gemm(
    const float* __restrict__ X, const float* __restrict__ W,
    const float* __restrict__ bias, float* __restrict__ C) {
  __shared__ float Xs[32][68];
  __shared__ float Ws[32][68];
  const int i0 = blockIdx.x * 64;
  const int j0 = blockIdx.y * 64;
  const int t = threadIdx.x;
  const int tx = t & 15, ty = t >> 4;
  float acc[4][4] = {};
  for (int d0 = 0; d0 < DM; d0 += 32) {
#pragma unroll
    for (int p = 0; p < 2; ++p) {
      int idx = t * 2 + p;            // 0..511
      int r = idx >> 3;               // 0..63
      int c4 = (idx & 7) * 4;         // 0..28
      float4 xv = *(const float4*)&X[(size_t)(i0 + r) * DM + d0 + c4];
      Xs[c4 + 0][r] = xv.x; Xs[c4 + 1][r] = xv.y;
      Xs[c4 + 2][r] = xv.z; Xs[c4 + 3][r] = xv.w;
      float4 wv = *(const float4*)&W[(size_t)(j0 + r) * DM + d0 + c4];
      Ws[c4 + 0][r] = wv.x; Ws[c4 + 1][r] = wv.y;
      Ws[c4 + 2][r] = wv.z; Ws[c4 + 3][r] = wv.w;
    }
    __syncthreads();
#pragma unroll
    for (int kk = 0; kk < 32; ++kk) {
      float a[4], b[4];
      *(float4*)a = *(const float4*)&Xs[kk][ty * 4];
      *(float4*)b = *(const float4*)&Ws[kk][tx * 4];
#pragma unroll
      for (int ii = 0; ii < 4; ++ii)
#pragma unroll
        for (int jj = 0; jj < 4; ++jj)
          acc[ii][jj] = fmaf(a[ii], b[jj], acc[ii][jj]);
    }
    __syncthreads();
  }
  float4 bv = *(const float4*)&bias[j0 + tx * 4];
#pragma unroll
  for (int ii = 0; ii < 4; ++ii) {
    int i = i0 + ty * 4 + ii;
    float4 o;
    o.x = acc[ii][0] + bv.x; o.y = acc[ii][1] + bv.y;
    o.z = acc[ii][2] + bv.z; o.w = acc[ii][3] + bv.w;
    *(float4*)&C[(size_t)i * DM + j0 + tx * 4] = o;
  }
}

// ---------------------------------------------------------------------------
// K2: per batch b: S[n,m] = merge(mask(q_b . k_b^T / sqrt(512)))
// Also accumulates aux scores (K=64) in a second accumulator set.
// ---------------------------------------------------------------------------
__global__ __launch_bounds__(256) void scores_kernel(
    const float* __restrict__ Q, const float* __restrict__ Kp,
    const float* __restrict__ QA, const float* __restrict__ KA,
    const int* __restrict__ adj, const float* __restrict__ mc_p,
    const float* __restrict__ thr_p, float* __restrict__ S) {
  __shared__ float Qs[32][68];
  __shared__ float Ks[32][68];
  const int b = blockIdx.z;
  const int n0 = blockIdx.x * 64;
  const int m0 = blockIdx.y * 64;
  const float* Qb = Q + (size_t)b * SEQ * DM;
  const float* Kb = Kp + (size_t)b * SEQ * DM;
  const float* QAb = QA + (size_t)b * SEQ * DAUX;
  const float* KAb = KA + (size_t)b * SEQ * DAUX;
  const int t = threadIdx.x;
  const int tx = t & 15, ty = t >> 4;
  float acc[4][4] = {};
  float aacc[4][4] = {};
  // main QK^T over K=512
  for (int d0 = 0; d0 < DM; d0 += 32) {
#pragma unroll
    for (int p = 0; p < 2; ++p) {
      int idx = t * 2 + p;
      int r = idx >> 3;
      int c4 = (idx & 7) * 4;
      float4 qv = *(const float4*)&Qb[(size_t)(n0 + r) * DM + d0 + c4];
      Qs[c4 + 0][r] = qv.x; Qs[c4 + 1][r] = qv.y;
      Qs[c4 + 2][r] = qv.z; Qs[c4 + 3][r] = qv.w;
      float4 kv = *(const float4*)&Kb[(size_t)(m0 + r) * DM + d0 + c4];
      Ks[c4 + 0][r] = kv.x; Ks[c4 + 1][r] = kv.y;
      Ks[c4 + 2][r] = kv.z; Ks[c4 + 3][r] = kv.w;
    }
    __syncthreads();
#pragma unroll
    for (int kk = 0; kk < 32; ++kk) {
      float a[4], b2[4];
      *(float4*)a = *(const float4*)&Qs[kk][ty * 4];
      *(float4*)b2 = *(const float4*)&Ks[kk][tx * 4];
#pragma unroll
      for (int ii = 0; ii < 4; ++ii)
#pragma unroll
        for (int jj = 0; jj < 4; ++jj)
          acc[ii][jj] = fmaf(a[ii], b2[jj], acc[ii][jj]);
    }
    __syncthreads();
  }
  // aux scores over K=64
  for (int d0 = 0; d0 < DAUX; d0 += 32) {
#pragma unroll
    for (int p = 0; p < 2; ++p) {
      int idx = t * 2 + p;
      int r = idx >> 3;
      int c4 = (idx & 7) * 4;
      float4 qv = *(const float4*)&QAb[(size_t)(n0 + r) * DAUX + d0 + c4];
      Qs[c4 + 0][r] = qv.x; Qs[c4 + 1][r] = qv.y;
      Qs[c4 + 2][r] = qv.z; Qs[c4 + 3][r] = qv.w;
      float4 kv = *(const float4*)&KAb[(size_t)(m0 + r) * DAUX + d0 + c4];
      Ks[c4 + 0][r] = kv.x; Ks[c4 + 1][r] = kv.y;
      Ks[c4 + 2][r] = kv.z; Ks[c4 + 3][r] = kv.w;
    }
    __syncthreads();
#pragma unroll
    for (int kk = 0; kk < 32; ++kk) {
      float a[4], b2[4];
      *(float4*)a = *(const float4*)&Qs[kk][ty * 4];
      *(float4*)b2 = *(const float4*)&Ks[kk][tx * 4];
#pragma unroll
      for (int ii = 0; ii < 4; ++ii)
#pragma unroll
        for (int jj = 0; jj < 4; ++jj)
          aacc[ii][jj] = fmaf(a[ii], b2[jj], aacc[ii][jj]);
    }
    __syncthreads();
  }
  const float mc = *mc_p;
  const float thr = *thr_p;
#pragma unroll
  for (int ii = 0; ii < 4; ++ii) {
    int n = n0 + ty * 4 + ii;
    const int* arow = adj + ((size_t)b * SEQ + n) * SEQ + m0 + tx * 4;
    int4 av = *(const int4*)arow;
    int am[4] = {av.x, av.y, av.z, av.w};
    float sv[4];
#pragma unroll
    for (int jj = 0; jj < 4; ++jj) {
      float s = acc[ii][jj] / 22.62741699796952f;   // / sqrt(512)
      float sa = aacc[ii][jj] * 0.125f;             // / sqrt(64), exact
      if (sa != 0.0f && s > thr) s = (1.0f - mc) * s + mc * sa;
      if (am[jj] == 0) s = MASKVAL;
      sv[jj] = s;
    }
    *(float4*)&S[((size_t)b * SEQ + n) * SEQ + m0 + tx * 4] = *(float4*)sv;
  }
}

// ---------------------------------------------------------------------------
// K3: per-row max and sum(exp(s - max)) over 2048 cols. One block per row.
// ---------------------------------------------------------------------------
__global__ __launch_bounds__(256) void softmax_stats(
    const float* __restrict__ S, float* __restrict__ rowmax,
    float* __restrict__ rowsum) {
  const int row = blockIdx.x;
  const float* Sr = S + (size_t)row * SEQ;
  const int t = threadIdx.x;
  float vals[8];
  float m = MASKVAL;
#pragma unroll
  for (int p = 0; p < 8; ++p) {
    vals[p] = Sr[t + p * 256];
    m = fmaxf(m, vals[p]);
  }
#pragma unroll
  for (int off = 32; off >= 1; off >>= 1) m = fmaxf(m, __shfl_down(m, off));
  __shared__ float wred[4];
  __shared__ float bmax;
  const int wave = t >> 6, lane = t & 63;
  if (lane == 0) wred[wave] = m;
  __syncthreads();
  if (t == 0) bmax = fmaxf(fmaxf(wred[0], wred[1]), fmaxf(wred[2], wred[3]));
  __syncthreads();
  const float mm = bmax;
  float s = 0.f;
#pragma unroll
  for (int p = 0; p < 8; ++p) s += __expf(vals[p] - mm);
#pragma unroll
  for (int off = 32; off >= 1; off >>= 1) s += __shfl_down(s, off);
  if (lane == 0) wred[wave] = s;
  __syncthreads();
  if (t == 0) {
    rowmax[row] = mm;
    rowsum[row] = wred[0] + wred[1] + wred[2] + wred[3];
  }
}

// ---------------------------------------------------------------------------
// K4: O[n,d] = (sum_m exp(S[n,m]-rowmax[n]) * V[m,d]) / rowsum[n]
// 64(n) x 128(d) block tile, 256 threads, 4x8 micro-tile, m-chunks of 32.
// ---------------------------------------------------------------------------
__global__ __launch_bounds__(256) void pv_gemm(
    const float* __restrict__ S, const float* __restrict__ V,
    const float* __restrict__ rowmax, const float* __restrict__ rowsum,
    float* __restrict__ O) {
  __shared__ float Ps[32][68];
  __shared__ float Vs[32][132];
  __shared__ float rm[64];
  const int b = blockIdx.z;
  const int n0 = blockIdx.x * 64;
  const int d0 = blockIdx.y * 128;
  const float* Sb = S + (size_t)b * SEQ * SEQ;
  const float* Vb = V + (size_t)b * SEQ * DM;
  const int t = threadIdx.x;
  if (t < 64) rm[t] = rowmax[b * SEQ + n0 + t];
  __syncthreads();
  const int tx = t & 15, ty = t >> 4;
  float acc[4][8] = {};
  for (int m0 = 0; m0 < SEQ; m0 += 32) {
#pragma unroll
    for (int p = 0; p < 2; ++p) {
      int idx = t * 2 + p;          // 0..511
      int r = idx >> 3;             // 0..63
      int c4 = (idx & 7) * 4;       // 0..28
      float4 sv = *(const float4*)&Sb[(size_t)(n0 + r) * SEQ + m0 + c4];
      float rmr = rm[r];
      Ps[c4 + 0][r] = __expf(sv.x - rmr);
      Ps[c4 + 1][r] = __expf(sv.y - rmr);
      Ps[c4 + 2][r] = __expf(sv.z - rmr);
      Ps[c4 + 3][r] = __expf(sv.w - rmr);
    }
#pragma unroll
    for (int p = 0; p < 4; ++p) {
      int idx = t * 4 + p;          // 0..1023
      int r = idx >> 5;             // 0..31
      int c4 = (idx & 31) * 4;      // 0..124
      *(float4*)&Vs[r][c4] = *(const float4*)&Vb[(size_t)(m0 + r) * DM + d0 + c4];
    }
    __syncthreads();
#pragma unroll
    for (int kk = 0; kk < 32; ++kk) {
      float a[4];
      *(float4*)a = *(const float4*)&Ps[kk][ty * 4];
      float bb[8];
      *(float4*)&bb[0] = *(const float4*)&Vs[kk][tx * 8];
      *(float4*)&bb[4] = *(const float4*)&Vs[kk][tx * 8 + 4];
#pragma unroll
      for (int ii = 0; ii < 4; ++ii)
#pragma unroll
        for (int jj = 0; jj < 8; ++jj)
          acc[ii][jj] = fmaf(a[ii], bb[jj], acc[ii][jj]);
    }
    __syncthreads();
  }
#pragma unroll
  for (int ii = 0; ii < 4; ++ii) {
    int n = n0 + ty * 4 + ii;
    float inv = 1.0f / rowsum[b * SEQ + n];
    float4 o0, o1;
    o0.x = acc[ii][0] * inv; o0.y = acc[ii][1] * inv;
    o0.z = acc[ii][2] * inv; o0.w = acc[ii][3] * inv;
    o1.x = acc[ii][4] * inv; o1.y = acc[ii][5] * inv;
    o1.z = acc[ii][6] * inv; o1.w = acc[ii][7] * inv;
    float* Orow = O + ((size_t)b * SEQ + n) * DM + d0 + tx * 8;
    *(float4*)&Orow[0] = o0;
    *(float4*)&Orow[4] = o1;
  }
}

// ---------------------------------------------------------------------------
extern "C" void kernel_launch(void* const* d_in, const int* in_sizes, int n_in,
                              void* d_out, int out_size, void* d_ws, size_t ws_size,
                              hipStream_t stream) {
  const float* x   = (const float*)d_in[0];
  const float* qa  = (const float*)d_in[1];
  const float* ka  = (const float*)d_in[2];
  const int*   adj = (const int*)d_in[3];
  const float* mc  = (const float*)d_in[4];
  const float* Wq  = (const float*)d_in[5];
  const float* bq  = (const float*)d_in[6];
  const float* Wk  = (const float*)d_in[7];
  const float* bk  = (const float*)d_in[8];
  const float* Wv  = (const float*)d_in[9];
  const float* bv  = (const float*)d_in[10];
  const float* thr = (const float*)d_in[11];
  float* out = (float*)d_out;

  float* ws = (float*)d_ws;
  float* q      = ws;                              // 8.39M floats
  float* k      = ws + (size_t)MROWS * DM;         // +8.39M
  float* v      = ws + (size_t)2 * MROWS * DM;     // +8.39M
  float* S      = ws + (size_t)3 * MROWS * DM;     // +33.55M
  float* rowmax = S + (size_t)MROWS * SEQ;         // +16K
  float* rowsum = rowmax + MROWS;                  // +16K  (total ~235 MB)

  dim3 blk(256);
  qkv_gemm<<<dim3(MROWS / 64, DM / 64), blk, 0, stream>>>(x, Wq, bq, q);
  qkv_gemm<<<dim3(MROWS / 64, DM / 64), blk, 0, stream>>>(x, Wk, bk, k);
  qkv_gemm<<<dim3(MROWS / 64, DM / 64), blk, 0, stream>>>(x, Wv, bv, v);
  scores_kernel<<<dim3(SEQ / 64, SEQ / 64, BATCH), blk, 0, stream>>>(
      q, k, qa, ka, adj, mc, thr, S);
  softmax_stats<<<dim3(MROWS), blk, 0, stream>>>(S, rowmax, rowsum);
  pv_gemm<<<dim3(SEQ / 64, DM / 128, BATCH), blk, 0, stream>>>(
      S, v, rowmax, rowsum, out);
}

// Round 2
// 609.619 us; speedup vs baseline: 2.5090x; 2.5090x over previous
//
#include <hip/hip_runtime.h>
#include <cstdint>

#define SEQ    2048
#define DM     512
#define DAUX   64
#define NBATCH 8
#define MASKVAL -3.402823466e38f

typedef _Float16 f16;
typedef __attribute__((ext_vector_type(2))) _Float16 f16x2;
typedef __attribute__((ext_vector_type(4))) _Float16 f16x4;
typedef __attribute__((ext_vector_type(8))) _Float16 f16x8;
typedef __attribute__((ext_vector_type(4))) float fx4;

// async global->LDS, 16B per lane. LDS dest must be wave-uniform base + lane*16.
__device__ __forceinline__ void g2l16(const void* g, void* l) {
  __builtin_amdgcn_global_load_lds(
      (__attribute__((address_space(1))) void*)const_cast<void*>(g),
      (__attribute__((address_space(3))) void*)l, 16, 0, 0);
}

// stage a 128x32 f16 tile (global row-major, rowstride in f16 elems) into packed LDS [128][32]
__device__ __forceinline__ void stage_tile(const f16* __restrict__ g0, int rowstride,
                                           f16* lds, int t) {
#pragma unroll
  for (int p = 0; p < 2; ++p) {
    int L = p * 256 + t;
    g2l16(g0 + (size_t)(L >> 2) * rowstride + (L & 3) * 8, lds + L * 8);
  }
}

// one K=32 chunk, split-f16 3-pass: acc += Ahi*Bhi + Ahi*Blo + Alo*Bhi  (64x64 per wave)
__device__ __forceinline__ void mfma_chunk3(const f16* __restrict__ Ahi, const f16* __restrict__ Alo,
                                            const f16* __restrict__ Bhi, const f16* __restrict__ Blo,
                                            fx4 acc[4][4], int wm, int wn, int lane) {
  const int r = lane & 15;
  const int q8 = (lane >> 4) * 8;
  f16x8 ah[4], al[4];
#pragma unroll
  for (int it = 0; it < 4; ++it) {
    int row = wm * 64 + it * 16 + r;
    ah[it] = *(const f16x8*)(Ahi + row * 32 + q8);
    al[it] = *(const f16x8*)(Alo + row * 32 + q8);
  }
#pragma unroll
  for (int jt = 0; jt < 4; ++jt) {
    int col = wn * 64 + jt * 16 + r;
    f16x8 bh = *(const f16x8*)(Bhi + col * 32 + q8);
    f16x8 bl = *(const f16x8*)(Blo + col * 32 + q8);
#pragma unroll
    for (int it = 0; it < 4; ++it) {
      acc[it][jt] = __builtin_amdgcn_mfma_f32_16x16x32_f16(ah[it], bh, acc[it][jt], 0, 0, 0);
      acc[it][jt] = __builtin_amdgcn_mfma_f32_16x16x32_f16(ah[it], bl, acc[it][jt], 0, 0, 0);
      acc[it][jt] = __builtin_amdgcn_mfma_f32_16x16x32_f16(al[it], bh, acc[it][jt], 0, 0, 0);
    }
  }
}

// ---------------------------------------------------------------------------
// Convert x and the 3 W matrices into scaled split-f16 (val*32 = hi + lo).
// ---------------------------------------------------------------------------
__device__ __forceinline__ void split_write(float v, f16* __restrict__ h, f16* __restrict__ l, size_t i) {
  float s = v * 32.0f;
  f16 hi = (f16)s;
  h[i] = hi;
  l[i] = (f16)(s - (float)hi);
}

__global__ __launch_bounds__(256) void convert_split(
    const float* __restrict__ x, const float* __restrict__ Wq,
    const float* __restrict__ Wk, const float* __restrict__ Wv,
    f16* __restrict__ xh, f16* __restrict__ xl,
    f16* __restrict__ Wh, f16* __restrict__ Wl) {
  int idx = blockIdx.x * 256 + threadIdx.x;   // float4 index, 0..2293759
  const float* src; f16* dh; f16* dl; size_t off;
  if (idx < 2097152) { src = x; off = (size_t)idx; dh = xh; dl = xl; }
  else {
    int rr = idx - 2097152; int w = rr >> 16; int o = rr & 65535;
    src = (w == 0) ? Wq : (w == 1) ? Wk : Wv;
    off = (size_t)o; dh = Wh + (size_t)w * 262144; dl = Wl + (size_t)w * 262144;
  }
  float4 v = ((const float4*)src)[off];
  size_t e = off * 4;
  split_write(v.x, dh, dl, e);
  split_write(v.y, dh, dl, e + 1);
  split_write(v.z, dh, dl, e + 2);
  split_write(v.w, dh, dl, e + 3);
}

// ---------------------------------------------------------------------------
// QKV: C = x*W^T + b, z selects Wq/Wk/Wv. Outputs scaled split-f16.
// z=2 (V) is written transposed: vt[b][d][n], so PV is BT-form too.
// ---------------------------------------------------------------------------
__global__ __launch_bounds__(256) void qkv_mfma(
    const f16* __restrict__ xh, const f16* __restrict__ xl,
    const f16* __restrict__ Wh, const f16* __restrict__ Wl,
    const float* __restrict__ bq, const float* __restrict__ bk, const float* __restrict__ bv,
    f16* __restrict__ qh, f16* __restrict__ ql,
    f16* __restrict__ kh, f16* __restrict__ kl,
    f16* __restrict__ vth, f16* __restrict__ vtl) {
  __shared__ __align__(16) f16 sm[16384];
  f16 *Ahi = sm, *Alo = sm + 4096, *Bhi = sm + 8192, *Blo = sm + 12288;
  const int t = threadIdx.x;
  const int i0 = blockIdx.x * 128;
  const int j0 = blockIdx.y * 128;
  const int z  = blockIdx.z;
  const f16* WhZ = Wh + (size_t)z * 262144;
  const f16* WlZ = Wl + (size_t)z * 262144;
  const int lane = t & 63, wave = t >> 6;
  const int wm = wave >> 1, wn = wave & 1;
  fx4 acc[4][4] = {};
  for (int d0 = 0; d0 < DM; d0 += 32) {
    __syncthreads();
    stage_tile(xh + (size_t)i0 * DM + d0, DM, Ahi, t);
    stage_tile(xl + (size_t)i0 * DM + d0, DM, Alo, t);
    stage_tile(WhZ + (size_t)j0 * DM + d0, DM, Bhi, t);
    stage_tile(WlZ + (size_t)j0 * DM + d0, DM, Blo, t);
    __syncthreads();
    mfma_chunk3(Ahi, Alo, Bhi, Blo, acc, wm, wn, lane);
  }
  const float* bias = (z == 0) ? bq : (z == 1) ? bk : bv;
  const int q4 = (lane >> 4) * 4, r15 = lane & 15;
  if (z < 2) {
    f16* oh = z ? kh : qh;  f16* ol = z ? kl : ql;
#pragma unroll
    for (int jt = 0; jt < 4; ++jt) {
      int j = j0 + wn * 64 + jt * 16 + r15;
      float bj = bias[j];
#pragma unroll
      for (int it = 0; it < 4; ++it) {
        int ib = i0 + wm * 64 + it * 16 + q4;
#pragma unroll
        for (int g = 0; g < 4; ++g) {
          float val = acc[it][jt][g] * (1.0f / 1024.0f) + bj;
          float s = val * 32.0f;
          f16 hi = (f16)s;
          oh[(size_t)(ib + g) * DM + j] = hi;
          ol[(size_t)(ib + g) * DM + j] = (f16)(s - (float)hi);
        }
      }
    }
  } else {
#pragma unroll
    for (int jt = 0; jt < 4; ++jt) {
      int j = j0 + wn * 64 + jt * 16 + r15;
      float bj = bias[j];
#pragma unroll
      for (int it = 0; it < 4; ++it) {
        int ib = i0 + wm * 64 + it * 16 + q4;
        int bb = ib >> 11, nb = ib & 2047;
        f16x4 hv, lv;
#pragma unroll
        for (int g = 0; g < 4; ++g) {
          float val = acc[it][jt][g] * (1.0f / 1024.0f) + bj;
          float s = val * 32.0f;
          f16 hi = (f16)s;
          hv[g] = hi; lv[g] = (f16)(s - (float)hi);
        }
        size_t base = ((size_t)(bb * DM + j)) * SEQ + nb;
        *(f16x4*)(vth + base) = hv;
        *(f16x4*)(vtl + base) = lv;
      }
    }
  }
}

// ---------------------------------------------------------------------------
// Scores: S = merge(mask(q.k^T/sqrt(512))). Main path split-f16 3-pass;
// aux (K=64) single-f16 computed first, parked packed in VGPRs.
// ---------------------------------------------------------------------------
__global__ __launch_bounds__(256) void scores_mfma(
    const f16* __restrict__ qh, const f16* __restrict__ ql,
    const f16* __restrict__ kh, const f16* __restrict__ kl,
    const float* __restrict__ qa, const float* __restrict__ ka,
    const int* __restrict__ adj,
    const float* __restrict__ mc_p, const float* __restrict__ thr_p,
    float* __restrict__ S) {
  __shared__ __align__(16) f16 sm[18432];
  f16 *Ahi = sm, *Alo = sm + 4096, *Bhi = sm + 8192, *Blo = sm + 12288;
  f16 *QAl = sm;                 // [128][72] padded (+8 breaks 16-bank aliasing)
  f16 *KAl = sm + 9216;
  const int t = threadIdx.x;
  const int n0 = blockIdx.x * 128, m0 = blockIdx.y * 128, b = blockIdx.z;
  const int lane = t & 63, wave = t >> 6;
  const int wm = wave >> 1, wn = wave & 1;
  const int r15 = lane & 15, qd = lane >> 4;

  // ---- aux phase: stage qa/ka as single f16 with in-kernel convert ----
  const float* QAb = qa + ((size_t)b * SEQ + n0) * DAUX;
  const float* KAb = ka + ((size_t)b * SEQ + m0) * DAUX;
#pragma unroll
  for (int p = 0; p < 4; ++p) {
    int L8 = p * 256 + t;
    int row = L8 >> 3, c8 = (L8 & 7) * 8;
    float4 u0 = *(const float4*)(QAb + (size_t)row * DAUX + c8);
    float4 u1 = *(const float4*)(QAb + (size_t)row * DAUX + c8 + 4);
    f16x8 hq = {(f16)u0.x,(f16)u0.y,(f16)u0.z,(f16)u0.w,(f16)u1.x,(f16)u1.y,(f16)u1.z,(f16)u1.w};
    *(f16x8*)(QAl + row * 72 + c8) = hq;
    float4 w0 = *(const float4*)(KAb + (size_t)row * DAUX + c8);
    float4 w1 = *(const float4*)(KAb + (size_t)row * DAUX + c8 + 4);
    f16x8 hk = {(f16)w0.x,(f16)w0.y,(f16)w0.z,(f16)w0.w,(f16)w1.x,(f16)w1.y,(f16)w1.z,(f16)w1.w};
    *(f16x8*)(KAl + row * 72 + c8) = hk;
  }
  __syncthreads();
  f16x2 sax[4][4][2];
  {
    const int q8 = qd * 8;
    f16x8 qa_f[4][2], ka_f[4][2];
#pragma unroll
    for (int it = 0; it < 4; ++it) {
      int row = wm * 64 + it * 16 + r15;
      qa_f[it][0] = *(const f16x8*)(QAl + row * 72 + q8);
      qa_f[it][1] = *(const f16x8*)(QAl + row * 72 + 32 + q8);
    }
#pragma unroll
    for (int jt = 0; jt < 4; ++jt) {
      int col = wn * 64 + jt * 16 + r15;
      ka_f[jt][0] = *(const f16x8*)(KAl + col * 72 + q8);
      ka_f[jt][1] = *(const f16x8*)(KAl + col * 72 + 32 + q8);
    }
#pragma unroll
    for (int it = 0; it < 4; ++it)
#pragma unroll
      for (int jt = 0; jt < 4; ++jt) {
        fx4 tmp = {0.f, 0.f, 0.f, 0.f};
        tmp = __builtin_amdgcn_mfma_f32_16x16x32_f16(qa_f[it][0], ka_f[jt][0], tmp, 0, 0, 0);
        tmp = __builtin_amdgcn_mfma_f32_16x16x32_f16(qa_f[it][1], ka_f[jt][1], tmp, 0, 0, 0);
        sax[it][jt][0] = f16x2{(f16)tmp[0], (f16)tmp[1]};
        sax[it][jt][1] = f16x2{(f16)tmp[2], (f16)tmp[3]};
      }
  }
  // ---- main QK^T, K=512 ----
  fx4 acc[4][4] = {};
  const f16* qhB = qh + ((size_t)b * SEQ + n0) * DM;
  const f16* qlB = ql + ((size_t)b * SEQ + n0) * DM;
  const f16* khB = kh + ((size_t)b * SEQ + m0) * DM;
  const f16* klB = kl + ((size_t)b * SEQ + m0) * DM;
  for (int d0 = 0; d0 < DM; d0 += 32) {
    __syncthreads();
    stage_tile(qhB + d0, DM, Ahi, t);
    stage_tile(qlB + d0, DM, Alo, t);
    stage_tile(khB + d0, DM, Bhi, t);
    stage_tile(klB + d0, DM, Blo, t);
    __syncthreads();
    mfma_chunk3(Ahi, Alo, Bhi, Blo, acc, wm, wn, lane);
  }
  // ---- merge + mask + store ----
  const float mc = *mc_p, thr = *thr_p;
  const float invC = 1.0f / (1024.0f * 22.62741699796952f);  // undo split-scale^2 and /sqrt(512)
#pragma unroll
  for (int it = 0; it < 4; ++it) {
    int rowb = n0 + wm * 64 + it * 16 + qd * 4;
#pragma unroll
    for (int g = 0; g < 4; ++g) {
      size_t rbase = ((size_t)b * SEQ + rowb + g) * SEQ;
#pragma unroll
      for (int jt = 0; jt < 4; ++jt) {
        int col = m0 + wn * 64 + jt * 16 + r15;
        float s = acc[it][jt][g] * invC;
        float sa = (float)sax[it][jt][g >> 1][g & 1] * 0.125f;
        if (sa != 0.0f && s > thr) s = (1.0f - mc) * s + mc * sa;
        if (adj[rbase + col] == 0) s = MASKVAL;
        S[rbase + col] = s;
      }
    }
  }
}

// ---------------------------------------------------------------------------
// Per-row softmax stats; overwrites each S row in place with P = exp(s-max)
// as scaled split-f16 ([2048 hi][2048 lo] in the row's 8KB), writes rowsum.
// ---------------------------------------------------------------------------
__global__ __launch_bounds__(256) void softmax_p(
    float* __restrict__ S, float* __restrict__ rowsum) {
  const size_t row = blockIdx.x;
  float* Sr = S + row * SEQ;
  const int t = threadIdx.x;
  float4 v0 = *(const float4*)(Sr + t * 8);
  float4 v1 = *(const float4*)(Sr + t * 8 + 4);
  float vals[8] = {v0.x, v0.y, v0.z, v0.w, v1.x, v1.y, v1.z, v1.w};
  float m = vals[0];
#pragma unroll
  for (int i = 1; i < 8; ++i) m = fmaxf(m, vals[i]);
#pragma unroll
  for (int off = 32; off >= 1; off >>= 1) m = fmaxf(m, __shfl_down(m, off, 64));
  __shared__ float wred[4];
  __shared__ float bmax;
  const int wv = t >> 6, ln = t & 63;
  if (ln == 0) wred[wv] = m;
  __syncthreads();
  if (t == 0) bmax = fmaxf(fmaxf(wred[0], wred[1]), fmaxf(wred[2], wred[3]));
  __syncthreads();
  const float mm = bmax;
  float p[8]; float z = 0.f;
#pragma unroll
  for (int i = 0; i < 8; ++i) { p[i] = __expf(vals[i] - mm); z += p[i]; }
#pragma unroll
  for (int off = 32; off >= 1; off >>= 1) z += __shfl_down(z, off, 64);
  __syncthreads();
  if (ln == 0) wred[wv] = z;
  __syncthreads();
  if (t == 0) rowsum[row] = wred[0] + wred[1] + wred[2] + wred[3];
  // all reads of Sr completed before the barriers above; safe to overwrite
  f16x8 hv, lv;
#pragma unroll
  for (int i = 0; i < 8; ++i) {
    float s = p[i] * 32.0f;
    f16 hi = (f16)s;
    hv[i] = hi; lv[i] = (f16)(s - (float)hi);
  }
  f16* Ph = (f16*)Sr;
  *(f16x8*)(Ph + t * 8) = hv;
  *(f16x8*)(Ph + 2048 + t * 8) = lv;
}

// ---------------------------------------------------------------------------
// PV: O[n][d] = (sum_m P[n][m] * vt[d][m]) / (1024 * Z[n]).  BT-form GEMM.
// ---------------------------------------------------------------------------
__global__ __launch_bounds__(256) void pv_mfma(
    const float* __restrict__ S, const f16* __restrict__ vth, const f16* __restrict__ vtl,
    const float* __restrict__ rowsum, float* __restrict__ O) {
  __shared__ __align__(16) f16 sm[16384];
  f16 *Phi = sm, *Plo = sm + 4096, *Bhi = sm + 8192, *Blo = sm + 12288;
  const int t = threadIdx.x;
  const int n0 = blockIdx.x * 128;
  const int d0 = blockIdx.y * 128;
  const int b  = blockIdx.z;
  const int lane = t & 63, wave = t >> 6;
  const int wm = wave >> 1, wn = wave & 1;
  fx4 acc[4][4] = {};
  const char* Srow0 = (const char*)(S + ((size_t)b * SEQ + n0) * SEQ);  // row stride 8192 B
  const f16* vhB = vth + ((size_t)(b * DM + d0)) * SEQ;
  const f16* vlB = vtl + ((size_t)(b * DM + d0)) * SEQ;
  for (int m0 = 0; m0 < SEQ; m0 += 32) {
    __syncthreads();
#pragma unroll
    for (int p = 0; p < 2; ++p) {
      int L = p * 256 + t;
      const char* g = Srow0 + (size_t)(L >> 2) * 8192 + (size_t)(m0 + (L & 3) * 8) * 2;
      g2l16(g, Phi + L * 8);
      g2l16(g + 4096, Plo + L * 8);
    }
    stage_tile(vhB + m0, SEQ, Bhi, t);
    stage_tile(vlB + m0, SEQ, Blo, t);
    __syncthreads();
    mfma_chunk3(Phi, Plo, Bhi, Blo, acc, wm, wn, lane);
  }
  const int r15 = lane & 15, qd = lane >> 4;
#pragma unroll
  for (int it = 0; it < 4; ++it) {
    int nb = n0 + wm * 64 + it * 16 + qd * 4;
#pragma unroll
    for (int g = 0; g < 4; ++g) {
      float inv = 1.0f / (1024.0f * rowsum[(size_t)b * SEQ + nb + g]);
      size_t obase = ((size_t)b * SEQ + nb + g) * DM;
#pragma unroll
      for (int jt = 0; jt < 4; ++jt) {
        int d = d0 + wn * 64 + jt * 16 + r15;
        O[obase + d] = acc[it][jt][g] * inv;
      }
    }
  }
}

// ---------------------------------------------------------------------------
extern "C" void kernel_launch(void* const* d_in, const int* in_sizes, int n_in,
                              void* d_out, int out_size, void* d_ws, size_t ws_size,
                              hipStream_t stream) {
  const float* x   = (const float*)d_in[0];
  const float* qa  = (const float*)d_in[1];
  const float* ka  = (const float*)d_in[2];
  const int*   adj = (const int*)d_in[3];
  const float* mc  = (const float*)d_in[4];
  const float* Wq  = (const float*)d_in[5];
  const float* bq  = (const float*)d_in[6];
  const float* Wk  = (const float*)d_in[7];
  const float* bk  = (const float*)d_in[8];
  const float* Wv  = (const float*)d_in[9];
  const float* bv  = (const float*)d_in[10];
  const float* thr = (const float*)d_in[11];
  float* out = (float*)d_out;

  // workspace layout (bytes):
  // [0, 96MB): q/k/vt split-f16 (6 x 16.78MB)
  // [96MB, +134.2MB): S (f32 scores, later split-f16 P) -- aliased during the
  //                   projection phase by x/W split-f16 (36.7MB, consumed before S written)
  // then rowsum (64KB). Total ~235MB.
  char* W = (char*)d_ws;
  f16* qh  = (f16*)W;
  f16* ql  = qh + 8388608;
  f16* kh  = ql + 8388608;
  f16* kl  = kh + 8388608;
  f16* vth = kl + 8388608;
  f16* vtl = vth + 8388608;
  float* S = (float*)(W + 100663296);
  float* rowsum = (float*)(W + 100663296 + 134217728);
  f16* xh = (f16*)S;               // aliases S region, dead before S is written
  f16* xl = xh + 8388608;
  f16* Wh = xl + 8388608;          // [3][512*512]
  f16* Wl = Wh + 786432;

  convert_split<<<8960, 256, 0, stream>>>(x, Wq, Wk, Wv, xh, xl, Wh, Wl);
  qkv_mfma<<<dim3(128, 4, 3), 256, 0, stream>>>(xh, xl, Wh, Wl, bq, bk, bv,
                                                qh, ql, kh, kl, vth, vtl);
  scores_mfma<<<dim3(16, 16, 8), 256, 0, stream>>>(qh, ql, kh, kl, qa, ka, adj, mc, thr, S);
  softmax_p<<<16384, 256, 0, stream>>>(S, rowsum);
  pv_mfma<<<dim3(16, 4, 8), 256, 0, stream>>>(S, vth, vtl, rowsum, out);
}

// Round 4
// 535.593 us; speedup vs baseline: 2.8558x; 1.1382x over previous
//
#include <hip/hip_runtime.h>
#include <cstdint>

#define SEQ    2048
#define DM     512
#define DAUX   64

typedef _Float16 f16;
typedef __attribute__((ext_vector_type(2))) _Float16 f16x2;
typedef __attribute__((ext_vector_type(4))) _Float16 f16x4;
typedef __attribute__((ext_vector_type(8))) _Float16 f16x8;
typedef __attribute__((ext_vector_type(4))) float fx4;

// async global->LDS, 16B per lane. LDS dest must be wave-uniform base + lane*16.
__device__ __forceinline__ void g2l16(const void* g, void* l) {
  __builtin_amdgcn_global_load_lds(
      (__attribute__((address_space(1))) void*)const_cast<void*>(g),
      (__attribute__((address_space(3))) void*)l, 16, 0, 0);
}

// Stage a 128x64 f16 tile into LDS with an XOR swizzle on 8-elem blocks:
// physical block jp at (row, jp) holds logical block jp ^ (row & 7).
// Destination stays lane-contiguous (global_load_lds constraint); source is free.
__device__ __forceinline__ void stage64(const f16* __restrict__ g0, int stride,
                                        f16* lds, int t) {
#pragma unroll
  for (int p = 0; p < 4; ++p) {
    int L = p * 256 + t;          // 0..1023
    int row = L >> 3;             // 0..127
    int jp = L & 7;               // physical 8-elem block
    int jl = jp ^ (row & 7);      // logical column block
    g2l16(g0 + (size_t)row * stride + jl * 8, lds + L * 8);
  }
}

__device__ __forceinline__ f16x8 frag64(const f16* lds, int row, int kq) {
  int jp = (kq >> 3) ^ (row & 7);
  return *(const f16x8*)(lds + row * 64 + jp * 8);
}

// K=64 chunk, 3-pass split: acc += Ah*Bh + Ah*Bl + Al*Bh.  64x64 per wave.
__device__ __forceinline__ void chunk3(const f16* Ah, const f16* Al,
                                       const f16* Bh, const f16* Bl,
                                       fx4 acc[4][4], int wm, int wn, int lane) {
  const int r15 = lane & 15;
  const int q8 = (lane >> 4) * 8;
#pragma unroll
  for (int k0 = 0; k0 < 64; k0 += 32) {
    f16x8 ah[4], al[4];
#pragma unroll
    for (int it = 0; it < 4; ++it) {
      int row = wm * 64 + it * 16 + r15;
      ah[it] = frag64(Ah, row, k0 + q8);
      al[it] = frag64(Al, row, k0 + q8);
    }
#pragma unroll
    for (int jt = 0; jt < 4; ++jt) {
      int col = wn * 64 + jt * 16 + r15;
      f16x8 bh = frag64(Bh, col, k0 + q8);
      f16x8 bl = frag64(Bl, col, k0 + q8);
#pragma unroll
      for (int it = 0; it < 4; ++it) {
        acc[it][jt] = __builtin_amdgcn_mfma_f32_16x16x32_f16(ah[it], bh, acc[it][jt], 0, 0, 0);
        acc[it][jt] = __builtin_amdgcn_mfma_f32_16x16x32_f16(ah[it], bl, acc[it][jt], 0, 0, 0);
        acc[it][jt] = __builtin_amdgcn_mfma_f32_16x16x32_f16(al[it], bh, acc[it][jt], 0, 0, 0);
      }
    }
  }
}

// K=64 chunk, single pass.
__device__ __forceinline__ void chunk1(const f16* A, const f16* B,
                                       fx4 acc[4][4], int wm, int wn, int lane) {
  const int r15 = lane & 15;
  const int q8 = (lane >> 4) * 8;
#pragma unroll
  for (int k0 = 0; k0 < 64; k0 += 32) {
    f16x8 a[4];
#pragma unroll
    for (int it = 0; it < 4; ++it)
      a[it] = frag64(A, wm * 64 + it * 16 + r15, k0 + q8);
#pragma unroll
    for (int jt = 0; jt < 4; ++jt) {
      f16x8 b = frag64(B, wn * 64 + jt * 16 + r15, k0 + q8);
#pragma unroll
      for (int it = 0; it < 4; ++it)
        acc[it][jt] = __builtin_amdgcn_mfma_f32_16x16x32_f16(a[it], b, acc[it][jt], 0, 0, 0);
    }
  }
}

// ---------------------------------------------------------------------------
// Convert: x and Wq/Wk/Wv -> scaled split f16 (v*32 = hi + lo). The x32
// scaling keeps lo terms out of the f16-denormal range (R2-verified).
// ---------------------------------------------------------------------------
__global__ __launch_bounds__(256) void convert_split(
    const float* __restrict__ x, const float* __restrict__ Wq,
    const float* __restrict__ Wk, const float* __restrict__ Wv,
    f16* __restrict__ xh, f16* __restrict__ xl,
    f16* __restrict__ Wh, f16* __restrict__ Wl) {
  int idx = blockIdx.x * 256 + threadIdx.x;   // float4 index, 0..2293759
  const float* src; f16* dh; f16* dl; size_t off;
  if (idx < 2097152) { src = x; off = (size_t)idx; dh = xh; dl = xl; }
  else {
    int rr = idx - 2097152;
    int w = rr >> 16, o = rr & 65535;
    src = (w == 0) ? Wq : (w == 1) ? Wk : Wv;
    off = (size_t)o;
    dh = Wh + (size_t)w * 262144; dl = Wl + (size_t)w * 262144;
  }
  float4 v = ((const float4*)src)[off];
  float vv[4] = {v.x, v.y, v.z, v.w};
  f16x4 hv, lv;
#pragma unroll
  for (int i = 0; i < 4; ++i) {
    float s = vv[i] * 32.0f;
    f16 hi = (f16)s;
    hv[i] = hi;
    lv[i] = (f16)(s - (float)hi);
  }
  *(f16x4*)(dh + off * 4) = hv;
  *(f16x4*)(dl + off * 4) = lv;
}

// ---------------------------------------------------------------------------
// QKV: C = x*W^T + b. z=0 -> q split (3-pass); z=1 -> k split (3-pass);
// z=2 -> v single f16 TRANSPOSED (1-pass; V only enters the output smoothly).
// ---------------------------------------------------------------------------
__global__ __launch_bounds__(256) void qkv_mfma(
    const f16* __restrict__ xh, const f16* __restrict__ xl,
    const f16* __restrict__ Wh, const f16* __restrict__ Wl,
    const float* __restrict__ bq, const float* __restrict__ bk, const float* __restrict__ bv,
    f16* __restrict__ qh, f16* __restrict__ ql,
    f16* __restrict__ kh, f16* __restrict__ kl,
    f16* __restrict__ vt) {
  __shared__ __align__(16) f16 sm[32768];   // 64 KB
  f16 *Ah = sm, *Al = sm + 8192, *Bh = sm + 16384, *Bl = sm + 24576;
  const int t = threadIdx.x;
  const int i0 = blockIdx.x * 128, j0 = blockIdx.y * 128, z = blockIdx.z;
  const f16* WhZ = Wh + (size_t)z * 262144;
  const f16* WlZ = Wl + (size_t)z * 262144;
  const int lane = t & 63, wave = t >> 6;
  const int wm = wave >> 1, wn = wave & 1;
  fx4 acc[4][4] = {};
  if (z < 2) {
    for (int d0 = 0; d0 < DM; d0 += 64) {
      __syncthreads();
      stage64(xh + (size_t)i0 * DM + d0, DM, Ah, t);
      stage64(xl + (size_t)i0 * DM + d0, DM, Al, t);
      stage64(WhZ + (size_t)j0 * DM + d0, DM, Bh, t);
      stage64(WlZ + (size_t)j0 * DM + d0, DM, Bl, t);
      __syncthreads();
      chunk3(Ah, Al, Bh, Bl, acc, wm, wn, lane);
    }
  } else {
    for (int d0 = 0; d0 < DM; d0 += 64) {
      __syncthreads();
      stage64(xh + (size_t)i0 * DM + d0, DM, Ah, t);
      stage64(WhZ + (size_t)j0 * DM + d0, DM, Bh, t);
      __syncthreads();
      chunk1(Ah, Bh, acc, wm, wn, lane);
    }
  }
  const float* bias = (z == 0) ? bq : (z == 1) ? bk : bv;
  const int q4 = (lane >> 4) * 4, r15 = lane & 15;
  if (z < 2) {
    f16* oh = z ? kh : qh;  f16* ol = z ? kl : ql;
#pragma unroll
    for (int jt = 0; jt < 4; ++jt) {
      int j = j0 + wn * 64 + jt * 16 + r15;
      float bj = bias[j];
#pragma unroll
      for (int it = 0; it < 4; ++it) {
        int ib = i0 + wm * 64 + it * 16 + q4;
#pragma unroll
        for (int g = 0; g < 4; ++g) {
          float val = acc[it][jt][g] * (1.0f / 1024.0f) + bj;   // exact f32 value
          float s = val * 32.0f;                                 // re-split, scaled
          f16 hi = (f16)s;
          oh[(size_t)(ib + g) * DM + j] = hi;
          ol[(size_t)(ib + g) * DM + j] = (f16)(s - (float)hi);
        }
      }
    }
  } else {
#pragma unroll
    for (int jt = 0; jt < 4; ++jt) {
      int j = j0 + wn * 64 + jt * 16 + r15;
      float bj = bias[j];
#pragma unroll
      for (int it = 0; it < 4; ++it) {
        int ib = i0 + wm * 64 + it * 16 + q4;
        int bb = ib >> 11, nb = ib & 2047;
        f16x4 hv;
#pragma unroll
        for (int g = 0; g < 4; ++g)
          hv[g] = (f16)(acc[it][jt][g] * (1.0f / 1024.0f) + bj);
        *(f16x4*)(vt + ((size_t)(bb * DM + j)) * SEQ + nb) = hv;
      }
    }
  }
}

// ---------------------------------------------------------------------------
// Scores: 3-pass split QK^T (f32-faithful at the threshold compare), aux
// single-f16, merge+mask in f32, then store S as f16 (post-compare, smooth).
// ---------------------------------------------------------------------------
__global__ __launch_bounds__(256) void scores_mfma(
    const f16* __restrict__ qh, const f16* __restrict__ ql,
    const f16* __restrict__ kh, const f16* __restrict__ kl,
    const float* __restrict__ qa, const float* __restrict__ ka,
    const int* __restrict__ adj,
    const float* __restrict__ mc_p, const float* __restrict__ thr_p,
    f16* __restrict__ S16) {
  __shared__ __align__(16) f16 sm[32768];   // 64 KB
  f16 *Ah = sm, *Al = sm + 8192, *Bh = sm + 16384, *Bl = sm + 24576;
  f16 *QAl = sm;                 // aux-phase union: [128][72] x2 = 36.9 KB
  f16 *KAl = sm + 9216;
  const int t = threadIdx.x;
  const int n0 = blockIdx.x * 128, m0 = blockIdx.y * 128, b = blockIdx.z;
  const int lane = t & 63, wave = t >> 6;
  const int wm = wave >> 1, wn = wave & 1;
  const int r15 = lane & 15, qd = lane >> 4;

  // ---- aux phase ----
  const float* QAb = qa + ((size_t)b * SEQ + n0) * DAUX;
  const float* KAb = ka + ((size_t)b * SEQ + m0) * DAUX;
#pragma unroll
  for (int p = 0; p < 4; ++p) {
    int L8 = p * 256 + t;
    int row = L8 >> 3, c8 = (L8 & 7) * 8;
    float4 u0 = *(const float4*)(QAb + (size_t)row * DAUX + c8);
    float4 u1 = *(const float4*)(QAb + (size_t)row * DAUX + c8 + 4);
    f16x8 hq = {(f16)u0.x,(f16)u0.y,(f16)u0.z,(f16)u0.w,(f16)u1.x,(f16)u1.y,(f16)u1.z,(f16)u1.w};
    *(f16x8*)(QAl + row * 72 + c8) = hq;
    float4 w0 = *(const float4*)(KAb + (size_t)row * DAUX + c8);
    float4 w1 = *(const float4*)(KAb + (size_t)row * DAUX + c8 + 4);
    f16x8 hk = {(f16)w0.x,(f16)w0.y,(f16)w0.z,(f16)w0.w,(f16)w1.x,(f16)w1.y,(f16)w1.z,(f16)w1.w};
    *(f16x8*)(KAl + row * 72 + c8) = hk;
  }
  __syncthreads();
  f16x2 sax[4][4][2];
  {
    const int q8 = qd * 8;
    f16x8 qa_f[4][2], ka_f[4][2];
#pragma unroll
    for (int it = 0; it < 4; ++it) {
      int row = wm * 64 + it * 16 + r15;
      qa_f[it][0] = *(const f16x8*)(QAl + row * 72 + q8);
      qa_f[it][1] = *(const f16x8*)(QAl + row * 72 + 32 + q8);
    }
#pragma unroll
    for (int jt = 0; jt < 4; ++jt) {
      int col = wn * 64 + jt * 16 + r15;
      ka_f[jt][0] = *(const f16x8*)(KAl + col * 72 + q8);
      ka_f[jt][1] = *(const f16x8*)(KAl + col * 72 + 32 + q8);
    }
#pragma unroll
    for (int it = 0; it < 4; ++it)
#pragma unroll
      for (int jt = 0; jt < 4; ++jt) {
        fx4 tmp = {0.f, 0.f, 0.f, 0.f};
        tmp = __builtin_amdgcn_mfma_f32_16x16x32_f16(qa_f[it][0], ka_f[jt][0], tmp, 0, 0, 0);
        tmp = __builtin_amdgcn_mfma_f32_16x16x32_f16(qa_f[it][1], ka_f[jt][1], tmp, 0, 0, 0);
        sax[it][jt][0] = f16x2{(f16)tmp[0], (f16)tmp[1]};
        sax[it][jt][1] = f16x2{(f16)tmp[2], (f16)tmp[3]};
      }
  }
  // ---- main QK^T, K=512, BK=64, 3-pass ----
  fx4 acc[4][4] = {};
  const f16* qhB = qh + ((size_t)b * SEQ + n0) * DM;
  const f16* qlB = ql + ((size_t)b * SEQ + n0) * DM;
  const f16* khB = kh + ((size_t)b * SEQ + m0) * DM;
  const f16* klB = kl + ((size_t)b * SEQ + m0) * DM;
  for (int d0 = 0; d0 < DM; d0 += 64) {
    __syncthreads();
    stage64(qhB + d0, DM, Ah, t);
    stage64(qlB + d0, DM, Al, t);
    stage64(khB + d0, DM, Bh, t);
    stage64(klB + d0, DM, Bl, t);
    __syncthreads();
    chunk3(Ah, Al, Bh, Bl, acc, wm, wn, lane);
  }
  // ---- merge + mask + f16 store ----
  const float mc = *mc_p, thr = *thr_p;
  const float invC = 1.0f / (1024.0f * 22.62741699796952f);  // /(32*32)/sqrt(512)
#pragma unroll
  for (int it = 0; it < 4; ++it) {
    int rowb = n0 + wm * 64 + it * 16 + qd * 4;
#pragma unroll
    for (int g = 0; g < 4; ++g) {
      size_t rbase = ((size_t)b * SEQ + rowb + g) * SEQ;
#pragma unroll
      for (int jt = 0; jt < 4; ++jt) {
        int col = m0 + wn * 64 + jt * 16 + r15;
        float s = acc[it][jt][g] * invC;
        float sa = (float)sax[it][jt][g >> 1][g & 1] * 0.125f;
        if (sa != 0.0f && s > thr) s = (1.0f - mc) * s + mc * sa;
        if (adj[rbase + col] == 0) s = -65504.0f;   // f16 min -> exp()==0
        S16[rbase + col] = (f16)s;
      }
    }
  }
}

// ---------------------------------------------------------------------------
// Softmax: in-place S16 row -> P16 = 1024*exp(s-max) (f16); rowsum = sum of
// the ROUNDED P16, so pv's normalization is exact by construction.
// ---------------------------------------------------------------------------
__global__ __launch_bounds__(256) void softmax_p(
    f16* __restrict__ S16, float* __restrict__ rowsum) {
  const size_t row = blockIdx.x;
  f16* Sr = S16 + row * SEQ;
  const int t = threadIdx.x;
  f16x8 v = *(const f16x8*)(Sr + t * 8);
  float vals[8];
#pragma unroll
  for (int i = 0; i < 8; ++i) vals[i] = (float)v[i];
  float m = vals[0];
#pragma unroll
  for (int i = 1; i < 8; ++i) m = fmaxf(m, vals[i]);
#pragma unroll
  for (int off = 32; off >= 1; off >>= 1) m = fmaxf(m, __shfl_down(m, off, 64));
  __shared__ float wred[4];
  __shared__ float bmax;
  const int wv = t >> 6, ln = t & 63;
  if (ln == 0) wred[wv] = m;
  __syncthreads();
  if (t == 0) bmax = fmaxf(fmaxf(wred[0], wred[1]), fmaxf(wred[2], wred[3]));
  __syncthreads();
  const float mm = bmax;
  f16x8 p16;
  float z = 0.f;
#pragma unroll
  for (int i = 0; i < 8; ++i) {
    f16 p = (f16)(__expf(vals[i] - mm) * 1024.0f);
    p16[i] = p;
    z += (float)p;
  }
#pragma unroll
  for (int off = 32; off >= 1; off >>= 1) z += __shfl_down(z, off, 64);
  __syncthreads();
  if (ln == 0) wred[wv] = z;
  __syncthreads();
  if (t == 0) rowsum[row] = wred[0] + wred[1] + wred[2] + wred[3];
  *(f16x8*)(Sr + t * 8) = p16;   // each thread rewrites only its own 16B
}

// ---------------------------------------------------------------------------
// PV (1-pass): O[n][d] = (sum_m P16[n][m] * vt[d][m]) / rowsum[n].
// ---------------------------------------------------------------------------
__global__ __launch_bounds__(256) void pv_mfma(
    const f16* __restrict__ P16, const f16* __restrict__ vt,
    const float* __restrict__ rowsum, float* __restrict__ O) {
  __shared__ __align__(16) f16 sm[16384];   // 32 KB
  f16 *Ps = sm, *Vs = sm + 8192;
  const int t = threadIdx.x;
  const int n0 = blockIdx.x * 128, d0 = blockIdx.y * 128, b = blockIdx.z;
  const int lane = t & 63, wave = t >> 6;
  const int wm = wave >> 1, wn = wave & 1;
  fx4 acc[4][4] = {};
  const f16* Pb = P16 + ((size_t)b * SEQ + n0) * SEQ;
  const f16* Vb = vt + ((size_t)b * DM + d0) * SEQ;
  for (int m0 = 0; m0 < SEQ; m0 += 64) {
    __syncthreads();
    stage64(Pb + m0, SEQ, Ps, t);
    stage64(Vb + m0, SEQ, Vs, t);
    __syncthreads();
    chunk1(Ps, Vs, acc, wm, wn, lane);
  }
  const int r15 = lane & 15, qd = lane >> 4;
#pragma unroll
  for (int it = 0; it < 4; ++it) {
    int nb = n0 + wm * 64 + it * 16 + qd * 4;
#pragma unroll
    for (int g = 0; g < 4; ++g) {
      float inv = 1.0f / rowsum[(size_t)b * SEQ + nb + g];
      size_t obase = ((size_t)b * SEQ + nb + g) * DM;
#pragma unroll
      for (int jt = 0; jt < 4; ++jt) {
        int d = d0 + wn * 64 + jt * 16 + r15;
        O[obase + d] = acc[it][jt][g] * inv;
      }
    }
  }
}

// ---------------------------------------------------------------------------
extern "C" void kernel_launch(void* const* d_in, const int* in_sizes, int n_in,
                              void* d_out, int out_size, void* d_ws, size_t ws_size,
                              hipStream_t stream) {
  const float* x   = (const float*)d_in[0];
  const float* qa  = (const float*)d_in[1];
  const float* ka  = (const float*)d_in[2];
  const int*   adj = (const int*)d_in[3];
  const float* mc  = (const float*)d_in[4];
  const float* Wq  = (const float*)d_in[5];
  const float* bq  = (const float*)d_in[6];
  const float* Wk  = (const float*)d_in[7];
  const float* bk  = (const float*)d_in[8];
  const float* Wv  = (const float*)d_in[9];
  const float* bv  = (const float*)d_in[10];
  const float* thr = (const float*)d_in[11];
  float* out = (float*)d_out;

  // ws layout (f16 elems): qh|ql|kh|kl|vt (8.39M each) | S16 (33.55M) | rowsum
  // convert outputs xh/xl/Wh/Wl alias the S16 region (dead before S16 written).
  f16* qh  = (f16*)d_ws;
  f16* ql  = qh + 8388608;
  f16* kh  = ql + 8388608;
  f16* kl  = kh + 8388608;
  f16* vt  = kl + 8388608;
  f16* S16 = vt + 8388608;
  float* rowsum = (float*)(S16 + 33554432);
  f16* xh = S16;                 // alias
  f16* xl = xh + 8388608;
  f16* Wh = xl + 8388608;        // [3][512*512]
  f16* Wl = Wh + 786432;

  convert_split<<<8960, 256, 0, stream>>>(x, Wq, Wk, Wv, xh, xl, Wh, Wl);
  qkv_mfma<<<dim3(128, 4, 3), 256, 0, stream>>>(xh, xl, Wh, Wl, bq, bk, bv,
                                                qh, ql, kh, kl, vt);
  scores_mfma<<<dim3(16, 16, 8), 256, 0, stream>>>(qh, ql, kh, kl, qa, ka, adj,
                                                   mc, thr, S16);
  softmax_p<<<16384, 256, 0, stream>>>(S16, rowsum);
  pv_mfma<<<dim3(16, 4, 8), 256, 0, stream>>>(S16, vt, rowsum, out);
}

// Round 5
// 506.844 us; speedup vs baseline: 3.0178x; 1.0567x over previous
//
#include <hip/hip_runtime.h>
#include <cstdint>

#define SEQ    2048
#define DM     512
#define DAUX   64

typedef _Float16 f16;
typedef __attribute__((ext_vector_type(2))) _Float16 f16x2;
typedef __attribute__((ext_vector_type(4))) _Float16 f16x4;
typedef __attribute__((ext_vector_type(8))) _Float16 f16x8;
typedef __attribute__((ext_vector_type(4))) float fx4;
typedef __attribute__((ext_vector_type(16))) float fx16;

// async global->LDS, 16B per lane. LDS dest must be wave-uniform base + lane*16.
__device__ __forceinline__ void g2l16(const void* g, void* l) {
  __builtin_amdgcn_global_load_lds(
      (__attribute__((address_space(1))) void*)const_cast<void*>(g),
      (__attribute__((address_space(3))) void*)l, 16, 0, 0);
}

// ---- BK=32 tile [128][32] with XOR swizzle jl = jp ^ ((row>>1)&3).
// Bank math: row stride 64B (16 banks); (row>>1)&3 spreads the 4 blocks so any
// 16-lane group covers all 32 banks exactly 2x (2-way = free, m136).
__device__ __forceinline__ void stage32(const f16* __restrict__ g0, int stride,
                                        f16* lds, int t) {
#pragma unroll
  for (int p = 0; p < 2; ++p) {
    int L = p * 256 + t;          // 0..511
    int row = L >> 2;             // 0..127
    int jp = L & 3;               // physical 8-elem block
    int jl = jp ^ ((row >> 1) & 3);
    g2l16(g0 + (size_t)row * stride + jl * 8, lds + L * 8);
  }
}
__device__ __forceinline__ f16x8 frag32(const f16* lds, int row, int kq) {
  int jp = (kq >> 3) ^ ((row >> 1) & 3);
  return *(const f16x8*)(lds + row * 32 + jp * 8);
}

// ---- BK=64 tile [128][64], swizzle jl = jp ^ (row&7) (row stride = 32 banks,
// full wrap: 8-block spread gives 2-way = free). R4-verified.
__device__ __forceinline__ void stage64(const f16* __restrict__ g0, int stride,
                                        f16* lds, int t) {
#pragma unroll
  for (int p = 0; p < 4; ++p) {
    int L = p * 256 + t;          // 0..1023
    int row = L >> 3;
    int jp = L & 7;
    int jl = jp ^ (row & 7);
    g2l16(g0 + (size_t)row * stride + jl * 8, lds + L * 8);
  }
}
__device__ __forceinline__ f16x8 frag64(const f16* lds, int row, int kq) {
  int jp = (kq >> 3) ^ (row & 7);
  return *(const f16x8*)(lds + row * 64 + jp * 8);
}

// ---- 32x32x16 MFMA chunks. Wave tile 64x64 = 2x2 of 32x32.
// A/B per-lane: [m = lane&31][k = (lane>>5)*8 + j].
// C/D per-lane: col = lane&31, row = (reg&3) + 8*(reg>>2) + 4*(lane>>5).
__device__ __forceinline__ void chunk3_32(const f16* Ah, const f16* Al,
                                          const f16* Bh, const f16* Bl,
                                          fx16 acc[2][2], int wm, int wn, int lane) {
  const int r31 = lane & 31;
  const int kq = (lane >> 5) * 8;
#pragma unroll
  for (int k0 = 0; k0 < 32; k0 += 16) {
    f16x8 ah[2], al[2];
#pragma unroll
    for (int it = 0; it < 2; ++it) {
      int row = wm * 64 + it * 32 + r31;
      ah[it] = frag32(Ah, row, k0 + kq);
      al[it] = frag32(Al, row, k0 + kq);
    }
#pragma unroll
    for (int jt = 0; jt < 2; ++jt) {
      int col = wn * 64 + jt * 32 + r31;
      f16x8 bh = frag32(Bh, col, k0 + kq);
      f16x8 bl = frag32(Bl, col, k0 + kq);
#pragma unroll
      for (int it = 0; it < 2; ++it) {
        acc[it][jt] = __builtin_amdgcn_mfma_f32_32x32x16_f16(ah[it], bh, acc[it][jt], 0, 0, 0);
        acc[it][jt] = __builtin_amdgcn_mfma_f32_32x32x16_f16(ah[it], bl, acc[it][jt], 0, 0, 0);
        acc[it][jt] = __builtin_amdgcn_mfma_f32_32x32x16_f16(al[it], bh, acc[it][jt], 0, 0, 0);
      }
    }
  }
}

__device__ __forceinline__ void chunk1_64(const f16* A, const f16* B,
                                          fx16 acc[2][2], int wm, int wn, int lane) {
  const int r31 = lane & 31;
  const int kq = (lane >> 5) * 8;
#pragma unroll
  for (int k0 = 0; k0 < 64; k0 += 16) {
    f16x8 a[2];
#pragma unroll
    for (int it = 0; it < 2; ++it)
      a[it] = frag64(A, wm * 64 + it * 32 + r31, k0 + kq);
#pragma unroll
    for (int jt = 0; jt < 2; ++jt) {
      f16x8 b = frag64(B, wn * 64 + jt * 32 + r31, k0 + kq);
#pragma unroll
      for (int it = 0; it < 2; ++it)
        acc[it][jt] = __builtin_amdgcn_mfma_f32_32x32x16_f16(a[it], b, acc[it][jt], 0, 0, 0);
    }
  }
}

// ---------------------------------------------------------------------------
// Convert: x and Wq/Wk/Wv -> scaled split f16 (v*32 = hi + lo; x32 keeps lo
// out of f16-denormal range).
// ---------------------------------------------------------------------------
__global__ __launch_bounds__(256) void convert_split(
    const float* __restrict__ x, const float* __restrict__ Wq,
    const float* __restrict__ Wk, const float* __restrict__ Wv,
    f16* __restrict__ xh, f16* __restrict__ xl,
    f16* __restrict__ Wh, f16* __restrict__ Wl) {
  int idx = blockIdx.x * 256 + threadIdx.x;   // float4 index, 0..2293759
  const float* src; f16* dh; f16* dl; size_t off;
  if (idx < 2097152) { src = x; off = (size_t)idx; dh = xh; dl = xl; }
  else {
    int rr = idx - 2097152;
    int w = rr >> 16, o = rr & 65535;
    src = (w == 0) ? Wq : (w == 1) ? Wk : Wv;
    off = (size_t)o;
    dh = Wh + (size_t)w * 262144; dl = Wl + (size_t)w * 262144;
  }
  float4 v = ((const float4*)src)[off];
  float vv[4] = {v.x, v.y, v.z, v.w};
  f16x4 hv, lv;
#pragma unroll
  for (int i = 0; i < 4; ++i) {
    float s = vv[i] * 32.0f;
    f16 hi = (f16)s;
    hv[i] = hi;
    lv[i] = (f16)(s - (float)hi);
  }
  *(f16x4*)(dh + off * 4) = hv;
  *(f16x4*)(dl + off * 4) = lv;
}

// ---------------------------------------------------------------------------
// QKV: C = x*W^T + b. z=0 -> q split (3-pass); z=1 -> k split (3-pass);
// z=2 -> v single f16 TRANSPOSED (1-pass; V enters the output smoothly).
// ---------------------------------------------------------------------------
__global__ __launch_bounds__(256) void qkv_mfma(
    const f16* __restrict__ xh, const f16* __restrict__ xl,
    const f16* __restrict__ Wh, const f16* __restrict__ Wl,
    const float* __restrict__ bq, const float* __restrict__ bk, const float* __restrict__ bv,
    f16* __restrict__ qh, f16* __restrict__ ql,
    f16* __restrict__ kh, f16* __restrict__ kl,
    f16* __restrict__ vt) {
  __shared__ __align__(16) f16 sm[16384];   // 32 KB
  const int t = threadIdx.x;
  const int i0 = blockIdx.x * 128, j0 = blockIdx.y * 128, z = blockIdx.z;
  const f16* WhZ = Wh + (size_t)z * 262144;
  const f16* WlZ = Wl + (size_t)z * 262144;
  const int lane = t & 63, wave = t >> 6;
  const int wm = wave >> 1, wn = wave & 1;
  const int r31 = lane & 31, half = lane >> 5;
  fx16 acc[2][2] = {};
  if (z < 2) {
    f16 *Ah = sm, *Al = sm + 4096, *Bh = sm + 8192, *Bl = sm + 12288;
    for (int d0 = 0; d0 < DM; d0 += 32) {
      __syncthreads();
      stage32(xh + (size_t)i0 * DM + d0, DM, Ah, t);
      stage32(xl + (size_t)i0 * DM + d0, DM, Al, t);
      stage32(WhZ + (size_t)j0 * DM + d0, DM, Bh, t);
      stage32(WlZ + (size_t)j0 * DM + d0, DM, Bl, t);
      __syncthreads();
      chunk3_32(Ah, Al, Bh, Bl, acc, wm, wn, lane);
    }
  } else {
    f16 *Ah = sm, *Bh = sm + 8192;
    for (int d0 = 0; d0 < DM; d0 += 64) {
      __syncthreads();
      stage64(xh + (size_t)i0 * DM + d0, DM, Ah, t);
      stage64(WhZ + (size_t)j0 * DM + d0, DM, Bh, t);
      __syncthreads();
      chunk1_64(Ah, Bh, acc, wm, wn, lane);
    }
  }
  const float* bias = (z == 0) ? bq : (z == 1) ? bk : bv;
  if (z < 2) {
    f16* oh = z ? kh : qh;  f16* ol = z ? kl : ql;
#pragma unroll
    for (int it = 0; it < 2; ++it)
#pragma unroll
      for (int jt = 0; jt < 2; ++jt) {
        int j = j0 + wn * 64 + jt * 32 + r31;
        float bj = bias[j];
#pragma unroll
        for (int r = 0; r < 16; ++r) {
          int ib = i0 + wm * 64 + it * 32 + (r & 3) + 8 * (r >> 2) + 4 * half;
          float val = acc[it][jt][r] * (1.0f / 1024.0f) + bj;   // exact f32 value
          float s = val * 32.0f;                                 // re-split, scaled
          f16 hi = (f16)s;
          oh[(size_t)ib * DM + j] = hi;
          ol[(size_t)ib * DM + j] = (f16)(s - (float)hi);
        }
      }
  } else {
#pragma unroll
    for (int it = 0; it < 2; ++it)
#pragma unroll
      for (int jt = 0; jt < 2; ++jt) {
        int j = j0 + wn * 64 + jt * 32 + r31;
        float bj = bias[j];
#pragma unroll
        for (int q4 = 0; q4 < 4; ++q4) {
          int ib = i0 + wm * 64 + it * 32 + 8 * q4 + 4 * half;   // 4 consecutive rows
          int bb = ib >> 11, nb = ib & 2047;
          f16x4 hv;
#pragma unroll
          for (int g = 0; g < 4; ++g)
            hv[g] = (f16)(acc[it][jt][q4 * 4 + g] * (1.0f / 1024.0f) + bj);
          *(f16x4*)(vt + ((size_t)(bb * DM + j)) * SEQ + nb) = hv;
        }
      }
  }
}

// ---------------------------------------------------------------------------
// Scores: 3-pass split QK^T (f32-faithful at the threshold compare), aux
// single-f16 (32x32 so sax shares the acc lane layout), merge+mask in f32,
// store S as f16 (post-compare, smooth).
// ---------------------------------------------------------------------------
__global__ __launch_bounds__(256) void scores_mfma(
    const f16* __restrict__ qh, const f16* __restrict__ ql,
    const f16* __restrict__ kh, const f16* __restrict__ kl,
    const float* __restrict__ qa, const float* __restrict__ ka,
    const int* __restrict__ adj,
    const float* __restrict__ mc_p, const float* __restrict__ thr_p,
    f16* __restrict__ S16) {
  __shared__ __align__(16) f16 sm[16384];   // 32 KB
  f16 *Ah = sm, *Al = sm + 4096, *Bh = sm + 8192, *Bl = sm + 12288;
  f16 *QAl = sm;                 // aux-phase union: [128][64] swizzled, 16 KB each
  f16 *KAl = sm + 8192;
  const int t = threadIdx.x;
  const int n0 = blockIdx.x * 128, m0 = blockIdx.y * 128, b = blockIdx.z;
  const int lane = t & 63, wave = t >> 6;
  const int wm = wave >> 1, wn = wave & 1;
  const int r31 = lane & 31, half = lane >> 5;
  const int kq = half * 8;

  // ---- aux phase: stage qa/ka as f16 into swizzled [128][64] ----
  const float* QAb = qa + ((size_t)b * SEQ + n0) * DAUX;
  const float* KAb = ka + ((size_t)b * SEQ + m0) * DAUX;
#pragma unroll
  for (int p = 0; p < 4; ++p) {
    int L8 = p * 256 + t;
    int row = L8 >> 3, jb = L8 & 7;
    int c8 = jb * 8;
    int jp = jb ^ (row & 7);                 // stage64-compatible swizzle
    float4 u0 = *(const float4*)(QAb + (size_t)row * DAUX + c8);
    float4 u1 = *(const float4*)(QAb + (size_t)row * DAUX + c8 + 4);
    f16x8 hq = {(f16)u0.x,(f16)u0.y,(f16)u0.z,(f16)u0.w,(f16)u1.x,(f16)u1.y,(f16)u1.z,(f16)u1.w};
    *(f16x8*)(QAl + row * 64 + jp * 8) = hq;
    float4 w0 = *(const float4*)(KAb + (size_t)row * DAUX + c8);
    float4 w1 = *(const float4*)(KAb + (size_t)row * DAUX + c8 + 4);
    f16x8 hk = {(f16)w0.x,(f16)w0.y,(f16)w0.z,(f16)w0.w,(f16)w1.x,(f16)w1.y,(f16)w1.z,(f16)w1.w};
    *(f16x8*)(KAl + row * 64 + jp * 8) = hk;
  }
  __syncthreads();
  f16x2 sax2[2][2][8];
  {
    fx16 aacc[2][2] = {};
#pragma unroll
    for (int k0 = 0; k0 < 64; k0 += 16) {
      f16x8 qaf[2];
#pragma unroll
      for (int it = 0; it < 2; ++it)
        qaf[it] = frag64(QAl, wm * 64 + it * 32 + r31, k0 + kq);
#pragma unroll
      for (int jt = 0; jt < 2; ++jt) {
        f16x8 kaf = frag64(KAl, wn * 64 + jt * 32 + r31, k0 + kq);
#pragma unroll
        for (int it = 0; it < 2; ++it)
          aacc[it][jt] = __builtin_amdgcn_mfma_f32_32x32x16_f16(qaf[it], kaf, aacc[it][jt], 0, 0, 0);
      }
    }
#pragma unroll
    for (int it = 0; it < 2; ++it)
#pragma unroll
      for (int jt = 0; jt < 2; ++jt)
#pragma unroll
        for (int r = 0; r < 16; ++r)
          sax2[it][jt][r >> 1][r & 1] = (f16)aacc[it][jt][r];
  }
  // ---- main QK^T, K=512, BK=32, 3-pass ----
  fx16 acc[2][2] = {};
  const f16* qhB = qh + ((size_t)b * SEQ + n0) * DM;
  const f16* qlB = ql + ((size_t)b * SEQ + n0) * DM;
  const f16* khB = kh + ((size_t)b * SEQ + m0) * DM;
  const f16* klB = kl + ((size_t)b * SEQ + m0) * DM;
  for (int d0 = 0; d0 < DM; d0 += 32) {
    __syncthreads();
    stage32(qhB + d0, DM, Ah, t);
    stage32(qlB + d0, DM, Al, t);
    stage32(khB + d0, DM, Bh, t);
    stage32(klB + d0, DM, Bl, t);
    __syncthreads();
    chunk3_32(Ah, Al, Bh, Bl, acc, wm, wn, lane);
  }
  // ---- merge + mask + f16 store ----
  const float mc = *mc_p, thr = *thr_p;
  const float invC = 1.0f / (1024.0f * 22.62741699796952f);  // /(32*32)/sqrt(512)
#pragma unroll
  for (int it = 0; it < 2; ++it)
#pragma unroll
    for (int jt = 0; jt < 2; ++jt) {
      int col = m0 + wn * 64 + jt * 32 + r31;
#pragma unroll
      for (int r = 0; r < 16; ++r) {
        int row = n0 + wm * 64 + it * 32 + (r & 3) + 8 * (r >> 2) + 4 * half;
        size_t rbase = ((size_t)b * SEQ + row) * SEQ;
        float s = acc[it][jt][r] * invC;
        float sa = (float)sax2[it][jt][r >> 1][r & 1] * 0.125f;
        if (sa != 0.0f && s > thr) s = (1.0f - mc) * s + mc * sa;
        if (adj[rbase + col] == 0) s = -65504.0f;   // f16 min -> exp()==0
        S16[rbase + col] = (f16)s;
      }
    }
}

// ---------------------------------------------------------------------------
// Softmax: in-place S16 row -> P16 = 1024*exp(s-max) (f16); rowsum = sum of
// the ROUNDED P16, so pv's normalization is exact by construction.
// ---------------------------------------------------------------------------
__global__ __launch_bounds__(256) void softmax_p(
    f16* __restrict__ S16, float* __restrict__ rowsum) {
  const size_t row = blockIdx.x;
  f16* Sr = S16 + row * SEQ;
  const int t = threadIdx.x;
  f16x8 v = *(const f16x8*)(Sr + t * 8);
  float vals[8];
#pragma unroll
  for (int i = 0; i < 8; ++i) vals[i] = (float)v[i];
  float m = vals[0];
#pragma unroll
  for (int i = 1; i < 8; ++i) m = fmaxf(m, vals[i]);
#pragma unroll
  for (int off = 32; off >= 1; off >>= 1) m = fmaxf(m, __shfl_down(m, off, 64));
  __shared__ float wred[4];
  __shared__ float bmax;
  const int wv = t >> 6, ln = t & 63;
  if (ln == 0) wred[wv] = m;
  __syncthreads();
  if (t == 0) bmax = fmaxf(fmaxf(wred[0], wred[1]), fmaxf(wred[2], wred[3]));
  __syncthreads();
  const float mm = bmax;
  f16x8 p16;
  float z = 0.f;
#pragma unroll
  for (int i = 0; i < 8; ++i) {
    f16 p = (f16)(__expf(vals[i] - mm) * 1024.0f);
    p16[i] = p;
    z += (float)p;
  }
#pragma unroll
  for (int off = 32; off >= 1; off >>= 1) z += __shfl_down(z, off, 64);
  __syncthreads();
  if (ln == 0) wred[wv] = z;
  __syncthreads();
  if (t == 0) rowsum[row] = wred[0] + wred[1] + wred[2] + wred[3];
  *(f16x8*)(Sr + t * 8) = p16;   // each thread rewrites only its own 16B
}

// ---------------------------------------------------------------------------
// PV (1-pass): O[n][d] = (sum_m P16[n][m] * vt[d][m]) / rowsum[n].
// ---------------------------------------------------------------------------
__global__ __launch_bounds__(256) void pv_mfma(
    const f16* __restrict__ P16, const f16* __restrict__ vt,
    const float* __restrict__ rowsum, float* __restrict__ O) {
  __shared__ __align__(16) f16 sm[16384];   // 32 KB
  f16 *Ps = sm, *Vs = sm + 8192;
  const int t = threadIdx.x;
  const int n0 = blockIdx.x * 128, d0 = blockIdx.y * 128, b = blockIdx.z;
  const int lane = t & 63, wave = t >> 6;
  const int wm = wave >> 1, wn = wave & 1;
  const int r31 = lane & 31, half = lane >> 5;
  fx16 acc[2][2] = {};
  const f16* Pb = P16 + ((size_t)b * SEQ + n0) * SEQ;
  const f16* Vb = vt + ((size_t)b * DM + d0) * SEQ;
  for (int m0 = 0; m0 < SEQ; m0 += 64) {
    __syncthreads();
    stage64(Pb + m0, SEQ, Ps, t);
    stage64(Vb + m0, SEQ, Vs, t);
    __syncthreads();
    chunk1_64(Ps, Vs, acc, wm, wn, lane);
  }
#pragma unroll
  for (int it = 0; it < 2; ++it)
#pragma unroll
    for (int jt = 0; jt < 2; ++jt) {
      int d = d0 + wn * 64 + jt * 32 + r31;
#pragma unroll
      for (int r = 0; r < 16; ++r) {
        int n = n0 + wm * 64 + it * 32 + (r & 3) + 8 * (r >> 2) + 4 * half;
        float inv = 1.0f / rowsum[(size_t)b * SEQ + n];
        O[((size_t)b * SEQ + n) * DM + d] = acc[it][jt][r] * inv;
      }
    }
}

// ---------------------------------------------------------------------------
extern "C" void kernel_launch(void* const* d_in, const int* in_sizes, int n_in,
                              void* d_out, int out_size, void* d_ws, size_t ws_size,
                              hipStream_t stream) {
  const float* x   = (const float*)d_in[0];
  const float* qa  = (const float*)d_in[1];
  const float* ka  = (const float*)d_in[2];
  const int*   adj = (const int*)d_in[3];
  const float* mc  = (const float*)d_in[4];
  const float* Wq  = (const float*)d_in[5];
  const float* bq  = (const float*)d_in[6];
  const float* Wk  = (const float*)d_in[7];
  const float* bk  = (const float*)d_in[8];
  const float* Wv  = (const float*)d_in[9];
  const float* bv  = (const float*)d_in[10];
  const float* thr = (const float*)d_in[11];
  float* out = (float*)d_out;

  // ws layout (f16 elems): qh|ql|kh|kl|vt (8.39M each) | S16 (33.55M) | rowsum
  // convert outputs xh/xl/Wh/Wl alias the S16 region (dead before S16 written).
  f16* qh  = (f16*)d_ws;
  f16* ql  = qh + 8388608;
  f16* kh  = ql + 8388608;
  f16* kl  = kh + 8388608;
  f16* vt  = kl + 8388608;
  f16* S16 = vt + 8388608;
  float* rowsum = (float*)(S16 + 33554432);
  f16* xh = S16;                 // alias
  f16* xl = xh + 8388608;
  f16* Wh = xl + 8388608;        // [3][512*512]
  f16* Wl = Wh + 786432;

  convert_split<<<8960, 256, 0, stream>>>(x, Wq, Wk, Wv, xh, xl, Wh, Wl);
  qkv_mfma<<<dim3(128, 4, 3), 256, 0, stream>>>(xh, xl, Wh, Wl, bq, bk, bv,
                                                qh, ql, kh, kl, vt);
  scores_mfma<<<dim3(16, 16, 8), 256, 0, stream>>>(qh, ql, kh, kl, qa, ka, adj,
                                                   mc, thr, S16);
  softmax_p<<<16384, 256, 0, stream>>>(S16, rowsum);
  pv_mfma<<<dim3(16, 4, 8), 256, 0, stream>>>(S16, vt, rowsum, out);
}

// Round 6
// 502.445 us; speedup vs baseline: 3.0442x; 1.0088x over previous
//
#include <hip/hip_runtime.h>
#include <cstdint>

#define SEQ    2048
#define DM     512
#define DAUX   64

typedef _Float16 f16;
typedef __attribute__((ext_vector_type(2))) _Float16 f16x2;
typedef __attribute__((ext_vector_type(4))) _Float16 f16x4;
typedef __attribute__((ext_vector_type(8))) _Float16 f16x8;
typedef __attribute__((ext_vector_type(4))) float fx4;
typedef __attribute__((ext_vector_type(16))) float fx16;

// async global->LDS, 16B per lane. LDS dest must be wave-uniform base + lane*16.
__device__ __forceinline__ void g2l16(const void* g, void* l) {
  __builtin_amdgcn_global_load_lds(
      (__attribute__((address_space(1))) void*)const_cast<void*>(g),
      (__attribute__((address_space(3))) void*)l, 16, 0, 0);
}

// ---- BK=32 tile [128][32], XOR swizzle on 8-elem blocks (jp ^ (row>>1)&3).
__device__ __forceinline__ void stage32(const f16* __restrict__ g0, int stride,
                                        f16* lds, int t) {
#pragma unroll
  for (int p = 0; p < 2; ++p) {
    int L = p * 256 + t;          // 0..511
    int row = L >> 2;             // 0..127
    int jp = L & 3;
    int jl = jp ^ ((row >> 1) & 3);
    g2l16(g0 + (size_t)row * stride + jl * 8, lds + L * 8);
  }
}
__device__ __forceinline__ f16x8 frag32(const f16* lds, int row, int kq) {
  int jp = (kq >> 3) ^ ((row >> 1) & 3);
  return *(const f16x8*)(lds + row * 32 + jp * 8);
}

// ---- BK=64 tile [128][64], swizzle jp ^ (row&7) (measured conflict-free, R4).
__device__ __forceinline__ void stage64(const f16* __restrict__ g0, int stride,
                                        f16* lds, int t) {
#pragma unroll
  for (int p = 0; p < 4; ++p) {
    int L = p * 256 + t;          // 0..1023
    int row = L >> 3;
    int jp = L & 7;
    int jl = jp ^ (row & 7);
    g2l16(g0 + (size_t)row * stride + jl * 8, lds + L * 8);
  }
}
__device__ __forceinline__ f16x8 frag64(const f16* lds, int row, int kq) {
  int jp = (kq >> 3) ^ (row & 7);
  return *(const f16x8*)(lds + row * 64 + jp * 8);
}

// ---- 32x32x16 MFMA chunks. Wave tile 64x64 = 2x2 of 32x32.
// A/B per-lane: [m = lane&31][k = (lane>>5)*8 + j].
// C/D per-lane: col = lane&31, row = (reg&3) + 8*(reg>>2) + 4*(lane>>5).
__device__ __forceinline__ void chunk3_32(const f16* Ah, const f16* Al,
                                          const f16* Bh, const f16* Bl,
                                          fx16 acc[2][2], int wm, int wn, int lane) {
  const int r31 = lane & 31;
  const int kq = (lane >> 5) * 8;
#pragma unroll
  for (int k0 = 0; k0 < 32; k0 += 16) {
    f16x8 ah[2], al[2];
#pragma unroll
    for (int it = 0; it < 2; ++it) {
      int row = wm * 64 + it * 32 + r31;
      ah[it] = frag32(Ah, row, k0 + kq);
      al[it] = frag32(Al, row, k0 + kq);
    }
#pragma unroll
    for (int jt = 0; jt < 2; ++jt) {
      int col = wn * 64 + jt * 32 + r31;
      f16x8 bh = frag32(Bh, col, k0 + kq);
      f16x8 bl = frag32(Bl, col, k0 + kq);
#pragma unroll
      for (int it = 0; it < 2; ++it) {
        acc[it][jt] = __builtin_amdgcn_mfma_f32_32x32x16_f16(ah[it], bh, acc[it][jt], 0, 0, 0);
        acc[it][jt] = __builtin_amdgcn_mfma_f32_32x32x16_f16(ah[it], bl, acc[it][jt], 0, 0, 0);
        acc[it][jt] = __builtin_amdgcn_mfma_f32_32x32x16_f16(al[it], bh, acc[it][jt], 0, 0, 0);
      }
    }
  }
}

__device__ __forceinline__ void chunk1_64(const f16* A, const f16* B,
                                          fx16 acc[2][2], int wm, int wn, int lane) {
  const int r31 = lane & 31;
  const int kq = (lane >> 5) * 8;
#pragma unroll
  for (int k0 = 0; k0 < 64; k0 += 16) {
    f16x8 a[2];
#pragma unroll
    for (int it = 0; it < 2; ++it)
      a[it] = frag64(A, wm * 64 + it * 32 + r31, k0 + kq);
#pragma unroll
    for (int jt = 0; jt < 2; ++jt) {
      f16x8 b = frag64(B, wn * 64 + jt * 32 + r31, k0 + kq);
#pragma unroll
      for (int it = 0; it < 2; ++it)
        acc[it][jt] = __builtin_amdgcn_mfma_f32_32x32x16_f16(a[it], b, acc[it][jt], 0, 0, 0);
    }
  }
}

// ---------------------------------------------------------------------------
// Convert: x and Wq/Wk/Wv -> scaled split f16 (v*32 = hi + lo).
// ---------------------------------------------------------------------------
__global__ __launch_bounds__(256) void convert_split(
    const float* __restrict__ x, const float* __restrict__ Wq,
    const float* __restrict__ Wk, const float* __restrict__ Wv,
    f16* __restrict__ xh, f16* __restrict__ xl,
    f16* __restrict__ Wh, f16* __restrict__ Wl) {
  int idx = blockIdx.x * 256 + threadIdx.x;   // float4 index, 0..2293759
  const float* src; f16* dh; f16* dl; size_t off;
  if (idx < 2097152) { src = x; off = (size_t)idx; dh = xh; dl = xl; }
  else {
    int rr = idx - 2097152;
    int w = rr >> 16, o = rr & 65535;
    src = (w == 0) ? Wq : (w == 1) ? Wk : Wv;
    off = (size_t)o;
    dh = Wh + (size_t)w * 262144; dl = Wl + (size_t)w * 262144;
  }
  float4 v = ((const float4*)src)[off];
  float vv[4] = {v.x, v.y, v.z, v.w};
  f16x4 hv, lv;
#pragma unroll
  for (int i = 0; i < 4; ++i) {
    float s = vv[i] * 32.0f;
    f16 hi = (f16)s;
    hv[i] = hi;
    lv[i] = (f16)(s - (float)hi);
  }
  *(f16x4*)(dh + off * 4) = hv;
  *(f16x4*)(dl + off * 4) = lv;
}

// ---------------------------------------------------------------------------
// QKV, double-buffered: C = x*W^T + b. z=0 -> q split; z=1 -> k split (both
// 3-pass); z=2 -> v single f16 TRANSPOSED (1-pass).
// ---------------------------------------------------------------------------
__global__ __launch_bounds__(256) void qkv_mfma(
    const f16* __restrict__ xh, const f16* __restrict__ xl,
    const f16* __restrict__ Wh, const f16* __restrict__ Wl,
    const float* __restrict__ bq, const float* __restrict__ bk, const float* __restrict__ bv,
    f16* __restrict__ qh, f16* __restrict__ ql,
    f16* __restrict__ kh, f16* __restrict__ kl,
    f16* __restrict__ vt) {
  __shared__ __align__(16) f16 sm[32768];   // 64 KB = 2 x 32 KB buffers
  const int t = threadIdx.x;
  const int i0 = blockIdx.x * 128, j0 = blockIdx.y * 128, z = blockIdx.z;
  const f16* WhZ = Wh + (size_t)z * 262144;
  const f16* WlZ = Wl + (size_t)z * 262144;
  const int lane = t & 63, wave = t >> 6;
  const int wm = wave >> 1, wn = wave & 1;
  const int r31 = lane & 31, half = lane >> 5;
  fx16 acc[2][2] = {};
  const f16* xhB = xh + (size_t)i0 * DM;
  const f16* xlB = xl + (size_t)i0 * DM;
  const f16* WhB = WhZ + (size_t)j0 * DM;
  const f16* WlB = WlZ + (size_t)j0 * DM;
  if (z < 2) {
    // prologue: chunk 0 into buf0
    stage32(xhB, DM, sm, t);
    stage32(xlB, DM, sm + 4096, t);
    stage32(WhB, DM, sm + 8192, t);
    stage32(WlB, DM, sm + 12288, t);
    __syncthreads();
    for (int c = 0; c < 16; ++c) {
      f16* cur = sm + (c & 1) * 16384;
      if (c < 15) {
        f16* nxt = sm + ((c + 1) & 1) * 16384;
        int d0 = (c + 1) * 32;
        stage32(xhB + d0, DM, nxt, t);
        stage32(xlB + d0, DM, nxt + 4096, t);
        stage32(WhB + d0, DM, nxt + 8192, t);
        stage32(WlB + d0, DM, nxt + 12288, t);
      }
      chunk3_32(cur, cur + 4096, cur + 8192, cur + 12288, acc, wm, wn, lane);
      if (c < 15) __syncthreads();
    }
  } else {
    stage64(xhB, DM, sm, t);
    stage64(WhB, DM, sm + 8192, t);
    __syncthreads();
    for (int c = 0; c < 8; ++c) {
      f16* cur = sm + (c & 1) * 16384;
      if (c < 7) {
        f16* nxt = sm + ((c + 1) & 1) * 16384;
        int d0 = (c + 1) * 64;
        stage64(xhB + d0, DM, nxt, t);
        stage64(WhB + d0, DM, nxt + 8192, t);
      }
      chunk1_64(cur, cur + 8192, acc, wm, wn, lane);
      if (c < 7) __syncthreads();
    }
  }
  const float* bias = (z == 0) ? bq : (z == 1) ? bk : bv;
  if (z < 2) {
    f16* oh = z ? kh : qh;  f16* ol = z ? kl : ql;
#pragma unroll
    for (int it = 0; it < 2; ++it)
#pragma unroll
      for (int jt = 0; jt < 2; ++jt) {
        int j = j0 + wn * 64 + jt * 32 + r31;
        float bj = bias[j];
#pragma unroll
        for (int r = 0; r < 16; ++r) {
          int ib = i0 + wm * 64 + it * 32 + (r & 3) + 8 * (r >> 2) + 4 * half;
          float val = acc[it][jt][r] * (1.0f / 1024.0f) + bj;   // exact f32 value
          float s = val * 32.0f;                                 // re-split, scaled
          f16 hi = (f16)s;
          oh[(size_t)ib * DM + j] = hi;
          ol[(size_t)ib * DM + j] = (f16)(s - (float)hi);
        }
      }
  } else {
#pragma unroll
    for (int it = 0; it < 2; ++it)
#pragma unroll
      for (int jt = 0; jt < 2; ++jt) {
        int j = j0 + wn * 64 + jt * 32 + r31;
        float bj = bias[j];
#pragma unroll
        for (int q4 = 0; q4 < 4; ++q4) {
          int ib = i0 + wm * 64 + it * 32 + 8 * q4 + 4 * half;   // 4 consecutive rows
          int bb = ib >> 11, nb = ib & 2047;
          f16x4 hv;
#pragma unroll
          for (int g = 0; g < 4; ++g)
            hv[g] = (f16)(acc[it][jt][q4 * 4 + g] * (1.0f / 1024.0f) + bj);
          *(f16x4*)(vt + ((size_t)(bb * DM + j)) * SEQ + nb) = hv;
        }
      }
  }
}

// ---------------------------------------------------------------------------
// Scores, double-buffered: 3-pass split QK^T (f32-faithful at the threshold
// compare); aux single-f16 in the prologue (hides chunk-0 staging); merge+mask
// in f32; store S f16.
// ---------------------------------------------------------------------------
__global__ __launch_bounds__(256) void scores_mfma(
    const f16* __restrict__ qh, const f16* __restrict__ ql,
    const f16* __restrict__ kh, const f16* __restrict__ kl,
    const float* __restrict__ qa, const float* __restrict__ ka,
    const int* __restrict__ adj,
    const float* __restrict__ mc_p, const float* __restrict__ thr_p,
    f16* __restrict__ S16) {
  __shared__ __align__(16) f16 sm[32768];   // 64 KB: buf0 | buf1 (aux uses buf1)
  const int t = threadIdx.x;
  const int n0 = blockIdx.x * 128, m0 = blockIdx.y * 128, b = blockIdx.z;
  const int lane = t & 63, wave = t >> 6;
  const int wm = wave >> 1, wn = wave & 1;
  const int r31 = lane & 31, half = lane >> 5;
  const int kq = half * 8;

  const f16* qhB = qh + ((size_t)b * SEQ + n0) * DM;
  const f16* qlB = ql + ((size_t)b * SEQ + n0) * DM;
  const f16* khB = kh + ((size_t)b * SEQ + m0) * DM;
  const f16* klB = kl + ((size_t)b * SEQ + m0) * DM;

  // ---- issue chunk-0 stage into buf0 (async; hidden behind aux phase) ----
  stage32(qhB, DM, sm, t);
  stage32(qlB, DM, sm + 4096, t);
  stage32(khB, DM, sm + 8192, t);
  stage32(klB, DM, sm + 12288, t);

  // ---- aux tiles into buf1 via plain stores ----
  f16* QAl = sm + 16384;   // [128][64] swizzled
  f16* KAl = sm + 24576;
  const float* QAb = qa + ((size_t)b * SEQ + n0) * DAUX;
  const float* KAb = ka + ((size_t)b * SEQ + m0) * DAUX;
#pragma unroll
  for (int p = 0; p < 4; ++p) {
    int L8 = p * 256 + t;
    int row = L8 >> 3, jb = L8 & 7;
    int c8 = jb * 8;
    int jp = jb ^ (row & 7);
    float4 u0 = *(const float4*)(QAb + (size_t)row * DAUX + c8);
    float4 u1 = *(const float4*)(QAb + (size_t)row * DAUX + c8 + 4);
    f16x8 hq = {(f16)u0.x,(f16)u0.y,(f16)u0.z,(f16)u0.w,(f16)u1.x,(f16)u1.y,(f16)u1.z,(f16)u1.w};
    *(f16x8*)(QAl + row * 64 + jp * 8) = hq;
    float4 w0 = *(const float4*)(KAb + (size_t)row * DAUX + c8);
    float4 w1 = *(const float4*)(KAb + (size_t)row * DAUX + c8 + 4);
    f16x8 hk = {(f16)w0.x,(f16)w0.y,(f16)w0.z,(f16)w0.w,(f16)w1.x,(f16)w1.y,(f16)w1.z,(f16)w1.w};
    *(f16x8*)(KAl + row * 64 + jp * 8) = hk;
  }
  __syncthreads();          // aux visible + chunk-0 loads drained

  // ---- aux MFMA phase (reads buf1) ----
  f16x2 sax2[2][2][8];
  {
    fx16 aacc[2][2] = {};
#pragma unroll
    for (int k0 = 0; k0 < 64; k0 += 16) {
      f16x8 qaf[2];
#pragma unroll
      for (int it = 0; it < 2; ++it)
        qaf[it] = frag64(QAl, wm * 64 + it * 32 + r31, k0 + kq);
#pragma unroll
      for (int jt = 0; jt < 2; ++jt) {
        f16x8 kaf = frag64(KAl, wn * 64 + jt * 32 + r31, k0 + kq);
#pragma unroll
        for (int it = 0; it < 2; ++it)
          aacc[it][jt] = __builtin_amdgcn_mfma_f32_32x32x16_f16(qaf[it], kaf, aacc[it][jt], 0, 0, 0);
      }
    }
#pragma unroll
    for (int it = 0; it < 2; ++it)
#pragma unroll
      for (int jt = 0; jt < 2; ++jt)
#pragma unroll
        for (int r = 0; r < 16; ++r)
          sax2[it][jt][r >> 1][r & 1] = (f16)aacc[it][jt][r];
  }
  __syncthreads();          // everyone done reading buf1 before c=0 prefetches into it

  // ---- main QK^T: 16 chunks, single barrier per chunk, prefetch-first ----
  fx16 acc[2][2] = {};
  for (int c = 0; c < 16; ++c) {
    f16* cur = sm + (c & 1) * 16384;
    if (c < 15) {
      f16* nxt = sm + ((c + 1) & 1) * 16384;
      int d0 = (c + 1) * 32;
      stage32(qhB + d0, DM, nxt, t);
      stage32(qlB + d0, DM, nxt + 4096, t);
      stage32(khB + d0, DM, nxt + 8192, t);
      stage32(klB + d0, DM, nxt + 12288, t);
    }
    chunk3_32(cur, cur + 4096, cur + 8192, cur + 12288, acc, wm, wn, lane);
    if (c < 15) __syncthreads();
  }

  // ---- merge + mask + f16 store ----
  const float mc = *mc_p, thr = *thr_p;
  const float invC = 1.0f / (1024.0f * 22.62741699796952f);  // /(32*32)/sqrt(512)
#pragma unroll
  for (int it = 0; it < 2; ++it)
#pragma unroll
    for (int jt = 0; jt < 2; ++jt) {
      int col = m0 + wn * 64 + jt * 32 + r31;
#pragma unroll
      for (int r = 0; r < 16; ++r) {
        int row = n0 + wm * 64 + it * 32 + (r & 3) + 8 * (r >> 2) + 4 * half;
        size_t rbase = ((size_t)b * SEQ + row) * SEQ;
        float s = acc[it][jt][r] * invC;
        float sa = (float)sax2[it][jt][r >> 1][r & 1] * 0.125f;
        if (sa != 0.0f && s > thr) s = (1.0f - mc) * s + mc * sa;
        if (adj[rbase + col] == 0) s = -65504.0f;   // f16 min -> exp()==0
        S16[rbase + col] = (f16)s;
      }
    }
}

// ---------------------------------------------------------------------------
// Softmax: one WAVE per row (4 rows/block, no barriers). In-place S16 row ->
// P16 = 1024*exp(s-max); rowsum = sum of the ROUNDED P16 (exact normalization).
// ---------------------------------------------------------------------------
__global__ __launch_bounds__(256) void softmax_p(
    f16* __restrict__ S16, float* __restrict__ rowsum) {
  const int wv = threadIdx.x >> 6, ln = threadIdx.x & 63;
  const size_t row = (size_t)blockIdx.x * 4 + wv;
  f16* Sr = S16 + row * SEQ;
  f16x8 v[4];
  float vals[32];
#pragma unroll
  for (int j = 0; j < 4; ++j) {
    v[j] = *(const f16x8*)(Sr + j * 512 + ln * 8);
#pragma unroll
    for (int i = 0; i < 8; ++i) vals[j * 8 + i] = (float)v[j][i];
  }
  float m = vals[0];
#pragma unroll
  for (int i = 1; i < 32; ++i) m = fmaxf(m, vals[i]);
#pragma unroll
  for (int off = 1; off < 64; off <<= 1) m = fmaxf(m, __shfl_xor(m, off, 64));
  float z = 0.f;
  f16x8 p16[4];
#pragma unroll
  for (int j = 0; j < 4; ++j)
#pragma unroll
    for (int i = 0; i < 8; ++i) {
      f16 p = (f16)(__expf(vals[j * 8 + i] - m) * 1024.0f);
      p16[j][i] = p;
      z += (float)p;
    }
#pragma unroll
  for (int off = 1; off < 64; off <<= 1) z += __shfl_xor(z, off, 64);
  if (ln == 0) rowsum[row] = z;
#pragma unroll
  for (int j = 0; j < 4; ++j)
    *(f16x8*)(Sr + j * 512 + ln * 8) = p16[j];
}

// ---------------------------------------------------------------------------
// PV, double-buffered (1-pass): O[n][d] = (sum_m P16[n][m]*vt[d][m])/rowsum[n].
// ---------------------------------------------------------------------------
__global__ __launch_bounds__(256) void pv_mfma(
    const f16* __restrict__ P16, const f16* __restrict__ vt,
    const float* __restrict__ rowsum, float* __restrict__ O) {
  __shared__ __align__(16) f16 sm[32768];   // 64 KB = 2 x (Ps 16KB + Vs 16KB)
  const int t = threadIdx.x;
  const int n0 = blockIdx.x * 128, d0 = blockIdx.y * 128, b = blockIdx.z;
  const int lane = t & 63, wave = t >> 6;
  const int wm = wave >> 1, wn = wave & 1;
  const int r31 = lane & 31, half = lane >> 5;
  fx16 acc[2][2] = {};
  const f16* Pb = P16 + ((size_t)b * SEQ + n0) * SEQ;
  const f16* Vb = vt + ((size_t)b * DM + d0) * SEQ;
  stage64(Pb, SEQ, sm, t);
  stage64(Vb, SEQ, sm + 8192, t);
  __syncthreads();
  for (int c = 0; c < 32; ++c) {
    f16* cur = sm + (c & 1) * 16384;
    if (c < 31) {
      f16* nxt = sm + ((c + 1) & 1) * 16384;
      int m0 = (c + 1) * 64;
      stage64(Pb + m0, SEQ, nxt, t);
      stage64(Vb + m0, SEQ, nxt + 8192, t);
    }
    chunk1_64(cur, cur + 8192, acc, wm, wn, lane);
    if (c < 31) __syncthreads();
  }
#pragma unroll
  for (int it = 0; it < 2; ++it)
#pragma unroll
    for (int jt = 0; jt < 2; ++jt) {
      int d = d0 + wn * 64 + jt * 32 + r31;
#pragma unroll
      for (int r = 0; r < 16; ++r) {
        int n = n0 + wm * 64 + it * 32 + (r & 3) + 8 * (r >> 2) + 4 * half;
        float inv = 1.0f / rowsum[(size_t)b * SEQ + n];
        O[((size_t)b * SEQ + n) * DM + d] = acc[it][jt][r] * inv;
      }
    }
}

// ---------------------------------------------------------------------------
extern "C" void kernel_launch(void* const* d_in, const int* in_sizes, int n_in,
                              void* d_out, int out_size, void* d_ws, size_t ws_size,
                              hipStream_t stream) {
  const float* x   = (const float*)d_in[0];
  const float* qa  = (const float*)d_in[1];
  const float* ka  = (const float*)d_in[2];
  const int*   adj = (const int*)d_in[3];
  const float* mc  = (const float*)d_in[4];
  const float* Wq  = (const float*)d_in[5];
  const float* bq  = (const float*)d_in[6];
  const float* Wk  = (const float*)d_in[7];
  const float* bk  = (const float*)d_in[8];
  const float* Wv  = (const float*)d_in[9];
  const float* bv  = (const float*)d_in[10];
  const float* thr = (const float*)d_in[11];
  float* out = (float*)d_out;

  // ws layout (f16 elems): qh|ql|kh|kl|vt (8.39M each) | S16 (33.55M) | rowsum
  // convert outputs xh/xl/Wh/Wl alias the S16 region (dead before S16 written).
  f16* qh  = (f16*)d_ws;
  f16* ql  = qh + 8388608;
  f16* kh  = ql + 8388608;
  f16* kl  = kh + 8388608;
  f16* vt  = kl + 8388608;
  f16* S16 = vt + 8388608;
  float* rowsum = (float*)(S16 + 33554432);
  f16* xh = S16;                 // alias
  f16* xl = xh + 8388608;
  f16* Wh = xl + 8388608;        // [3][512*512]
  f16* Wl = Wh + 786432;

  convert_split<<<8960, 256, 0, stream>>>(x, Wq, Wk, Wv, xh, xl, Wh, Wl);
  qkv_mfma<<<dim3(128, 4, 3), 256, 0, stream>>>(xh, xl, Wh, Wl, bq, bk, bv,
                                                qh, ql, kh, kl, vt);
  scores_mfma<<<dim3(16, 16, 8), 256, 0, stream>>>(qh, ql, kh, kl, qa, ka, adj,
                                                   mc, thr, S16);
  softmax_p<<<4096, 256, 0, stream>>>(S16, rowsum);
  pv_mfma<<<dim3(16, 4, 8), 256, 0, stream>>>(S16, vt, rowsum, out);
}